// Round 1
// baseline (1497.809 us; speedup 1.0000x reference)
//
#include <hip/hip_runtime.h>

#define N_NODES 8192
#define N_EDGES 262144
#define IN_DIM 256
#define HID 256
#define OUT_DIM 64
#define PATH_DIM 64
#define NHEADS 4
#define DH 16

// ---------------- graph setup ----------------

__global__ __launch_bounds__(256) void init_graph(int* deg, int* cursor) {
  int i = blockIdx.x * 256 + threadIdx.x;
  if (i < N_NODES) { deg[i] = 1; cursor[i] = 0; }   // deg starts at 1 (self loop)
}

__global__ __launch_bounds__(256) void count_deg(const int* __restrict__ dst,
                                                 int* __restrict__ deg) {
  int e = blockIdx.x * 256 + threadIdx.x;
  if (e < N_EDGES) atomicAdd(&deg[dst[e]], 1);
}

// single-block exclusive scan of (deg-1) -> row_off, plus dinv = rsqrt(deg)
__global__ __launch_bounds__(256) void scan_rows(const int* __restrict__ deg,
                                                 int* __restrict__ row_off,
                                                 float* __restrict__ dinv) {
  __shared__ int part[256];
  int t = threadIdx.x;
  int base = t * 32;
  int local[32];
  int s = 0;
  #pragma unroll
  for (int i = 0; i < 32; ++i) {
    int c = deg[base + i] - 1;
    local[i] = s;
    s += c;
  }
  part[t] = s;
  __syncthreads();
  // Hillis-Steele inclusive scan over 256 partials
  for (int d = 1; d < 256; d <<= 1) {
    int v = (t >= d) ? part[t - d] : 0;
    __syncthreads();
    part[t] += v;
    __syncthreads();
  }
  int prev = (t == 0) ? 0 : part[t - 1];
  #pragma unroll
  for (int i = 0; i < 32; ++i) {
    row_off[base + i] = prev + local[i];
    dinv[base + i] = rsqrtf((float)deg[base + i]);
  }
}

__global__ __launch_bounds__(256) void fill_csr(const int* __restrict__ src,
                                                const int* __restrict__ dst,
                                                const int* __restrict__ row_off,
                                                int* __restrict__ cursor,
                                                int* __restrict__ csr) {
  int e = blockIdx.x * 256 + threadIdx.x;
  if (e < N_EDGES) {
    int d = dst[e];
    int p = atomicAdd(&cursor[d], 1);
    csr[row_off[d] + p] = src[e];
  }
}

// ---------------- small utility ----------------

// W[R][C] -> Wt[C][R]
__global__ __launch_bounds__(256) void transpose_w(const float* __restrict__ W,
                                                   float* __restrict__ Wt,
                                                   int R, int C) {
  int i = blockIdx.x * 256 + threadIdx.x;
  if (i < R * C) {
    int r = i / C, c = i % C;
    Wt[c * R + r] = W[i];
  }
}

// ---------------- GEMM: C[M,N] = concat(A1,A2)[M,K1+K2] @ B[K,N] (+bias)(+relu) ----------------
// 64x64 tile, 256 threads, 4x4 micro-tile, BK=16. Requires K1 % 16 == 0, N % 64 == 0.

template <bool RELU, bool BIAS>
__global__ __launch_bounds__(256) void gemm_tile(const float* __restrict__ A1, int K1,
                                                 const float* __restrict__ A2, int K2,
                                                 const float* __restrict__ B,
                                                 const float* __restrict__ bias,
                                                 float* __restrict__ C, int N) {
  __shared__ __align__(16) float As[16][64];
  __shared__ __align__(16) float Bs[16][68];
  const int K = K1 + K2;
  const int bm = blockIdx.y * 64;
  const int bn = blockIdx.x * 64;
  const int t = threadIdx.x;
  const int tx = t & 15, ty = t >> 4;
  const int am = t >> 2;          // 0..63
  const int ak = (t & 3) << 2;    // 0,4,8,12
  const int bk = t >> 4;          // 0..15
  const int bn4 = (t & 15) << 2;  // 0..60
  float acc[4][4] = {};
  for (int k0 = 0; k0 < K; k0 += 16) {
    int kk = k0 + ak;
    int row = bm + am;
    float4 av;
    if (kk < K1)
      av = *reinterpret_cast<const float4*>(A1 + (size_t)row * K1 + kk);
    else
      av = *reinterpret_cast<const float4*>(A2 + (size_t)row * K2 + (kk - K1));
    As[ak + 0][am] = av.x;
    As[ak + 1][am] = av.y;
    As[ak + 2][am] = av.z;
    As[ak + 3][am] = av.w;
    float4 bv = *reinterpret_cast<const float4*>(B + (size_t)(k0 + bk) * N + bn + bn4);
    *reinterpret_cast<float4*>(&Bs[bk][bn4]) = bv;
    __syncthreads();
    #pragma unroll
    for (int k = 0; k < 16; ++k) {
      float4 a = *reinterpret_cast<const float4*>(&As[k][ty << 2]);
      float4 b = *reinterpret_cast<const float4*>(&Bs[k][tx << 2]);
      acc[0][0] += a.x * b.x; acc[0][1] += a.x * b.y; acc[0][2] += a.x * b.z; acc[0][3] += a.x * b.w;
      acc[1][0] += a.y * b.x; acc[1][1] += a.y * b.y; acc[1][2] += a.y * b.z; acc[1][3] += a.y * b.w;
      acc[2][0] += a.z * b.x; acc[2][1] += a.z * b.y; acc[2][2] += a.z * b.z; acc[2][3] += a.z * b.w;
      acc[3][0] += a.w * b.x; acc[3][1] += a.w * b.y; acc[3][2] += a.w * b.z; acc[3][3] += a.w * b.w;
    }
    __syncthreads();
  }
  #pragma unroll
  for (int i = 0; i < 4; ++i) {
    int row = bm + (ty << 2) + i;
    float4 o = make_float4(acc[i][0], acc[i][1], acc[i][2], acc[i][3]);
    if (BIAS) {
      float4 bv = *reinterpret_cast<const float4*>(bias + bn + (tx << 2));
      o.x += bv.x; o.y += bv.y; o.z += bv.z; o.w += bv.w;
    }
    if (RELU) {
      o.x = fmaxf(o.x, 0.f); o.y = fmaxf(o.y, 0.f);
      o.z = fmaxf(o.z, 0.f); o.w = fmaxf(o.w, 0.f);
    }
    *reinterpret_cast<float4*>(C + (size_t)row * N + bn + (tx << 2)) = o;
  }
}

// ---------------- attention ----------------
// grid: (128 qblocks, 4 heads), block: 256 threads = 4 waves.
// wave w handles keys [w*2048, (w+1)*2048), lane l = query qb*64+l.
// Streaming softmax without max subtraction (|score| <= ~0.6, exp safe).

__global__ __launch_bounds__(256) void attn_kernel(const float* __restrict__ qkv,
                                                   float* __restrict__ attn_out) {
  const int h = blockIdx.y;
  const int qb = blockIdx.x;
  const int t = threadIdx.x;
  const int w = t >> 6;
  const int l = t & 63;
  const int n = qb * 64 + l;

  const float* qp = qkv + (size_t)n * 192 + h * 16;
  float q[16];
  #pragma unroll
  for (int i = 0; i < 4; ++i) {
    float4 v4 = *reinterpret_cast<const float4*>(qp + i * 4);
    q[i * 4 + 0] = v4.x; q[i * 4 + 1] = v4.y; q[i * 4 + 2] = v4.z; q[i * 4 + 3] = v4.w;
  }

  float acc[16] = {};
  float wsum = 0.f;
  const int m0 = w * 2048, m1 = m0 + 2048;
  const float* kbase = qkv + 64 + h * 16;
  const float* vbase = qkv + 128 + h * 16;

  for (int m = m0; m < m1; ++m) {
    const float* kp = kbase + (size_t)m * 192;
    float4 k0 = *reinterpret_cast<const float4*>(kp + 0);
    float4 k1 = *reinterpret_cast<const float4*>(kp + 4);
    float4 k2 = *reinterpret_cast<const float4*>(kp + 8);
    float4 k3 = *reinterpret_cast<const float4*>(kp + 12);
    float s = q[0] * k0.x + q[1] * k0.y + q[2] * k0.z + q[3] * k0.w
            + q[4] * k1.x + q[5] * k1.y + q[6] * k1.z + q[7] * k1.w
            + q[8] * k2.x + q[9] * k2.y + q[10] * k2.z + q[11] * k2.w
            + q[12] * k3.x + q[13] * k3.y + q[14] * k3.z + q[15] * k3.w;
    float wgt = __expf(s * 0.25f);
    wsum += wgt;
    const float* vp = vbase + (size_t)m * 192;
    float4 v0 = *reinterpret_cast<const float4*>(vp + 0);
    float4 v1 = *reinterpret_cast<const float4*>(vp + 4);
    float4 v2 = *reinterpret_cast<const float4*>(vp + 8);
    float4 v3 = *reinterpret_cast<const float4*>(vp + 12);
    acc[0]  += wgt * v0.x; acc[1]  += wgt * v0.y; acc[2]  += wgt * v0.z; acc[3]  += wgt * v0.w;
    acc[4]  += wgt * v1.x; acc[5]  += wgt * v1.y; acc[6]  += wgt * v1.z; acc[7]  += wgt * v1.w;
    acc[8]  += wgt * v2.x; acc[9]  += wgt * v2.y; acc[10] += wgt * v2.z; acc[11] += wgt * v2.w;
    acc[12] += wgt * v3.x; acc[13] += wgt * v3.y; acc[14] += wgt * v3.z; acc[15] += wgt * v3.w;
  }

  __shared__ float red[4][64][17];
  #pragma unroll
  for (int d = 0; d < 16; ++d) red[w][l][d] = acc[d];
  red[w][l][16] = wsum;
  __syncthreads();

  if (t < 64) {
    float tot[16];
    float ws = 0.f;
    #pragma unroll
    for (int d = 0; d < 16; ++d) tot[d] = 0.f;
    #pragma unroll
    for (int w2 = 0; w2 < 4; ++w2) {
      ws += red[w2][t][16];
      #pragma unroll
      for (int d = 0; d < 16; ++d) tot[d] += red[w2][t][d];
    }
    float inv = 1.f / ws;
    int n2 = qb * 64 + t;
    float* op = attn_out + (size_t)n2 * 64 + h * 16;
    #pragma unroll
    for (int d = 0; d < 16; ++d) op[d] = tot[d] * inv;
  }
}

// ---------------- GCN aggregation ----------------
// out[r] = dinv[r] * ( dinv[r]*hw[r] + sum_{s in CSR[r]} dinv[s]*hw[s] ) + bias (+relu)
// one wave per destination row.

template <int C, bool RELU>
__global__ __launch_bounds__(256) void aggregate(const float* __restrict__ hw,
                                                 const int* __restrict__ csr,
                                                 const int* __restrict__ row_off,
                                                 const int* __restrict__ deg,
                                                 const float* __restrict__ dinv,
                                                 const float* __restrict__ bias,
                                                 float* __restrict__ out) {
  const int w = threadIdx.x >> 6, l = threadIdx.x & 63;
  const int r = blockIdx.x * 4 + w;
  const float dr = dinv[r];
  const int off = row_off[r];
  const int cnt = deg[r] - 1;

  if constexpr (C == 256) {
    const int c = l << 2;
    float4 a = *reinterpret_cast<const float4*>(hw + (size_t)r * C + c);
    float ax = dr * a.x, ay = dr * a.y, az = dr * a.z, aw = dr * a.w;
    for (int e = 0; e < cnt; ++e) {
      int s = csr[off + e];
      float ws = dinv[s];
      float4 hv = *reinterpret_cast<const float4*>(hw + (size_t)s * C + c);
      ax += ws * hv.x; ay += ws * hv.y; az += ws * hv.z; aw += ws * hv.w;
    }
    float4 bv = *reinterpret_cast<const float4*>(bias + c);
    float4 o;
    o.x = dr * ax + bv.x; o.y = dr * ay + bv.y;
    o.z = dr * az + bv.z; o.w = dr * aw + bv.w;
    if (RELU) {
      o.x = fmaxf(o.x, 0.f); o.y = fmaxf(o.y, 0.f);
      o.z = fmaxf(o.z, 0.f); o.w = fmaxf(o.w, 0.f);
    }
    *reinterpret_cast<float4*>(out + (size_t)r * C + c) = o;
  } else {  // C == 64
    float a = dr * hw[(size_t)r * C + l];
    for (int e = 0; e < cnt; ++e) {
      int s = csr[off + e];
      a += dinv[s] * hw[(size_t)s * C + l];
    }
    float o = dr * a + bias[l];
    if (RELU) o = fmaxf(o, 0.f);
    out[(size_t)r * C + l] = o;
  }
}

// ---------------- launch ----------------

extern "C" void kernel_launch(void* const* d_in, const int* in_sizes, int n_in,
                              void* d_out, int out_size, void* d_ws, size_t ws_size,
                              hipStream_t stream) {
  const float* x          = (const float*)d_in[0];
  const int*   ei         = (const int*)d_in[1];
  const float* pe_w       = (const float*)d_in[2];
  const float* pe_b       = (const float*)d_in[3];
  const float* in_proj_w  = (const float*)d_in[4];
  const float* in_proj_b  = (const float*)d_in[5];
  const float* out_proj_w = (const float*)d_in[6];
  const float* out_proj_b = (const float*)d_in[7];
  const float* w1         = (const float*)d_in[8];
  const float* b1         = (const float*)d_in[9];
  const float* w2         = (const float*)d_in[10];
  const float* b2         = (const float*)d_in[11];
  const float* w3         = (const float*)d_in[12];
  const float* b3         = (const float*)d_in[13];

  const int* esrc = ei;
  const int* edst = ei + N_EDGES;

  char* ws = (char*)d_ws;
  size_t o = 0;
  auto take = [&](size_t n) {
    char* p = ws + o;
    o += (n + 255) & ~(size_t)255;
    return p;
  };
  float* pf       = (float*)take((size_t)N_NODES * PATH_DIM * 4);
  float* qkv      = (float*)take((size_t)N_NODES * 3 * PATH_DIM * 4);
  float* attn_out = (float*)take((size_t)N_NODES * PATH_DIM * 4);
  float* pa       = (float*)take((size_t)N_NODES * PATH_DIM * 4);
  float* hw       = (float*)take((size_t)N_NODES * HID * 4);
  float* h1       = (float*)take((size_t)N_NODES * HID * 4);
  float* h2       = (float*)take((size_t)N_NODES * HID * 4);
  float* Wt_in    = (float*)take((size_t)3 * PATH_DIM * PATH_DIM * 4);
  float* Wt_out   = (float*)take((size_t)PATH_DIM * PATH_DIM * 4);
  float* dinv     = (float*)take((size_t)N_NODES * 4);
  int*   deg      = (int*)take((size_t)N_NODES * 4);
  int*   cursor   = (int*)take((size_t)N_NODES * 4);
  int*   row_off  = (int*)take((size_t)N_NODES * 4);
  int*   csr      = (int*)take((size_t)N_EDGES * 4);

  // graph preprocessing
  init_graph<<<N_NODES / 256, 256, 0, stream>>>(deg, cursor);
  count_deg<<<N_EDGES / 256, 256, 0, stream>>>(edst, deg);
  scan_rows<<<1, 256, 0, stream>>>(deg, row_off, dinv);
  fill_csr<<<N_EDGES / 256, 256, 0, stream>>>(esrc, edst, row_off, cursor, csr);

  // weight transposes (PyTorch-style x @ W.T)
  transpose_w<<<(192 * 64 + 255) / 256, 256, 0, stream>>>(in_proj_w, Wt_in, 192, 64);
  transpose_w<<<(64 * 64 + 255) / 256, 256, 0, stream>>>(out_proj_w, Wt_out, 64, 64);

  // pf = x @ pe_w + pe_b          [8192,256]x[256,64]
  gemm_tile<false, true><<<dim3(1, 128), 256, 0, stream>>>(x, IN_DIM, nullptr, 0, pe_w, pe_b, pf, PATH_DIM);
  // qkv = pf @ Wt_in + in_proj_b  [8192,64]x[64,192]
  gemm_tile<false, true><<<dim3(3, 128), 256, 0, stream>>>(pf, PATH_DIM, nullptr, 0, Wt_in, in_proj_b, qkv, 3 * PATH_DIM);
  // attention
  attn_kernel<<<dim3(128, 4), 256, 0, stream>>>(qkv, attn_out);
  // pa = attn_out @ Wt_out + out_proj_b
  gemm_tile<false, true><<<dim3(1, 128), 256, 0, stream>>>(attn_out, PATH_DIM, nullptr, 0, Wt_out, out_proj_b, pa, PATH_DIM);

  // layer 1: hw = [x, pa] @ w1 ; h1 = relu(aggregate + b1)
  gemm_tile<false, false><<<dim3(4, 128), 256, 0, stream>>>(x, IN_DIM, pa, PATH_DIM, w1, nullptr, hw, HID);
  aggregate<256, true><<<N_NODES / 4, 256, 0, stream>>>(hw, csr, row_off, deg, dinv, b1, h1);
  // layer 2
  gemm_tile<false, false><<<dim3(4, 128), 256, 0, stream>>>(h1, HID, nullptr, 0, w2, nullptr, hw, HID);
  aggregate<256, true><<<N_NODES / 4, 256, 0, stream>>>(hw, csr, row_off, deg, dinv, b2, h2);
  // layer 3 -> d_out
  gemm_tile<false, false><<<dim3(1, 128), 256, 0, stream>>>(h2, HID, nullptr, 0, w3, nullptr, hw, OUT_DIM);
  aggregate<64, false><<<N_NODES / 4, 256, 0, stream>>>(hw, csr, row_off, deg, dinv, b3, (float*)d_out);
}

// Round 2
// 376.707 us; speedup vs baseline: 3.9761x; 3.9761x over previous
//
#include <hip/hip_runtime.h>

#define N_NODES 8192
#define N_EDGES 262144
#define IN_DIM 256
#define HID 256
#define OUT_DIM 64
#define PATH_DIM 64
#define NHEADS 4
#define DH 16

typedef __attribute__((ext_vector_type(8))) short bf16x8;
typedef __attribute__((ext_vector_type(4))) float f32x4;

__device__ __forceinline__ short f2bf(float f) {
  union { float f; unsigned int u; } c;
  c.f = f;
  unsigned int u = c.u;
  u += 0x7fffu + ((u >> 16) & 1u);
  return (short)(u >> 16);
}

// ---------------- graph setup ----------------

__global__ __launch_bounds__(256) void init_graph(int* deg, int* cursor) {
  int i = blockIdx.x * 256 + threadIdx.x;
  if (i < N_NODES) { deg[i] = 1; cursor[i] = 0; }   // deg starts at 1 (self loop)
}

__global__ __launch_bounds__(256) void count_deg(const int* __restrict__ dst,
                                                 int* __restrict__ deg) {
  int e = blockIdx.x * 256 + threadIdx.x;
  if (e < N_EDGES) atomicAdd(&deg[dst[e]], 1);
}

__global__ __launch_bounds__(256) void scan_rows(const int* __restrict__ deg,
                                                 int* __restrict__ row_off,
                                                 float* __restrict__ dinv) {
  __shared__ int part[256];
  int t = threadIdx.x;
  int base = t * 32;
  int local[32];
  int s = 0;
  #pragma unroll
  for (int i = 0; i < 32; ++i) {
    int c = deg[base + i] - 1;
    local[i] = s;
    s += c;
  }
  part[t] = s;
  __syncthreads();
  for (int d = 1; d < 256; d <<= 1) {
    int v = (t >= d) ? part[t - d] : 0;
    __syncthreads();
    part[t] += v;
    __syncthreads();
  }
  int prev = (t == 0) ? 0 : part[t - 1];
  #pragma unroll
  for (int i = 0; i < 32; ++i) {
    row_off[base + i] = prev + local[i];
    dinv[base + i] = rsqrtf((float)deg[base + i]);
  }
}

__global__ __launch_bounds__(256) void fill_csr(const int* __restrict__ src,
                                                const int* __restrict__ dst,
                                                const int* __restrict__ row_off,
                                                int* __restrict__ cursor,
                                                int* __restrict__ csr) {
  int e = blockIdx.x * 256 + threadIdx.x;
  if (e < N_EDGES) {
    int d = dst[e];
    int p = atomicAdd(&cursor[d], 1);
    csr[row_off[d] + p] = src[e];
  }
}

// ---------------- small utility ----------------

__global__ __launch_bounds__(256) void transpose_w(const float* __restrict__ W,
                                                   float* __restrict__ Wt,
                                                   int R, int C) {
  int i = blockIdx.x * 256 + threadIdx.x;
  if (i < R * C) {
    int r = i / C, c = i % C;
    Wt[c * R + r] = W[i];
  }
}

// ---------------- fp32 GEMM (64x64 tile) ----------------

template <bool RELU, bool BIAS>
__global__ __launch_bounds__(256) void gemm_tile(const float* __restrict__ A1, int K1,
                                                 const float* __restrict__ A2, int K2,
                                                 const float* __restrict__ B,
                                                 const float* __restrict__ bias,
                                                 float* __restrict__ C, int N) {
  __shared__ __align__(16) float As[16][64];
  __shared__ __align__(16) float Bs[16][68];
  const int K = K1 + K2;
  const int bm = blockIdx.y * 64;
  const int bn = blockIdx.x * 64;
  const int t = threadIdx.x;
  const int tx = t & 15, ty = t >> 4;
  const int am = t >> 2;
  const int ak = (t & 3) << 2;
  const int bk = t >> 4;
  const int bn4 = (t & 15) << 2;
  float acc[4][4] = {};
  for (int k0 = 0; k0 < K; k0 += 16) {
    int kk = k0 + ak;
    int row = bm + am;
    float4 av;
    if (kk < K1)
      av = *reinterpret_cast<const float4*>(A1 + (size_t)row * K1 + kk);
    else
      av = *reinterpret_cast<const float4*>(A2 + (size_t)row * K2 + (kk - K1));
    As[ak + 0][am] = av.x;
    As[ak + 1][am] = av.y;
    As[ak + 2][am] = av.z;
    As[ak + 3][am] = av.w;
    float4 bv = *reinterpret_cast<const float4*>(B + (size_t)(k0 + bk) * N + bn + bn4);
    *reinterpret_cast<float4*>(&Bs[bk][bn4]) = bv;
    __syncthreads();
    #pragma unroll
    for (int k = 0; k < 16; ++k) {
      float4 a = *reinterpret_cast<const float4*>(&As[k][ty << 2]);
      float4 b = *reinterpret_cast<const float4*>(&Bs[k][tx << 2]);
      acc[0][0] += a.x * b.x; acc[0][1] += a.x * b.y; acc[0][2] += a.x * b.z; acc[0][3] += a.x * b.w;
      acc[1][0] += a.y * b.x; acc[1][1] += a.y * b.y; acc[1][2] += a.y * b.z; acc[1][3] += a.y * b.w;
      acc[2][0] += a.z * b.x; acc[2][1] += a.z * b.y; acc[2][2] += a.z * b.z; acc[2][3] += a.z * b.w;
      acc[3][0] += a.w * b.x; acc[3][1] += a.w * b.y; acc[3][2] += a.w * b.z; acc[3][3] += a.w * b.w;
    }
    __syncthreads();
  }
  #pragma unroll
  for (int i = 0; i < 4; ++i) {
    int row = bm + (ty << 2) + i;
    float4 o = make_float4(acc[i][0], acc[i][1], acc[i][2], acc[i][3]);
    if (BIAS) {
      float4 bv = *reinterpret_cast<const float4*>(bias + bn + (tx << 2));
      o.x += bv.x; o.y += bv.y; o.z += bv.z; o.w += bv.w;
    }
    if (RELU) {
      o.x = fmaxf(o.x, 0.f); o.y = fmaxf(o.y, 0.f);
      o.z = fmaxf(o.z, 0.f); o.w = fmaxf(o.w, 0.f);
    }
    *reinterpret_cast<float4*>(C + (size_t)row * N + bn + (tx << 2)) = o;
  }
}

// ---------------- MFMA flash attention ----------------
// grid (128 qblocks, 4 heads) x 256 threads (4 waves).
// Each wave owns 16 q-rows. Keys streamed in 64-key chunks via LDS (bf16).
// QK^T: 4x mfma_f32_16x16x32_bf16 with dh=16 zero-padded to K=32.
// PV:   P round-trips LDS (C-layout -> A-layout), 2x mfma per chunk.

__global__ __launch_bounds__(256) void attn_mfma(const float* __restrict__ qkv,
                                                 float* __restrict__ attn_out) {
  const int h = blockIdx.y;
  const int qb = blockIdx.x;
  const int t = threadIdx.x;
  const int wv = t >> 6;
  const int l = t & 63;
  const int lg = l >> 4;   // lane group 0..3
  const int lc = l & 15;   // lane col 0..15

  __shared__ __align__(16) short Ks[64][24];       // [key][dh] padded (48B rows)
  __shared__ __align__(16) short Vt[16][72];       // [dh][key] padded (144B rows)
  __shared__ __align__(16) short Ps[4][16][72];    // per-wave P [q][key] padded

  // Q A-fragment (lane: q-row lc, dh = lg*8+j for lg<2, zeros for lg>=2), pre-scaled by 0.25
  bf16x8 qfrag = {0, 0, 0, 0, 0, 0, 0, 0};
  {
    const int n = qb * 64 + wv * 16 + lc;
    if (lg < 2) {
      const float* qp = qkv + (size_t)n * 192 + h * 16 + lg * 8;
      float4 a = *reinterpret_cast<const float4*>(qp);
      float4 b = *reinterpret_cast<const float4*>(qp + 4);
      qfrag[0] = f2bf(a.x * 0.25f); qfrag[1] = f2bf(a.y * 0.25f);
      qfrag[2] = f2bf(a.z * 0.25f); qfrag[3] = f2bf(a.w * 0.25f);
      qfrag[4] = f2bf(b.x * 0.25f); qfrag[5] = f2bf(b.y * 0.25f);
      qfrag[6] = f2bf(b.z * 0.25f); qfrag[7] = f2bf(b.w * 0.25f);
    }
  }

  f32x4 oacc = {0.f, 0.f, 0.f, 0.f};
  float wsum[4] = {0.f, 0.f, 0.f, 0.f};

  const int skey = t >> 2;        // staging: row (key) 0..63
  const int sd = t & 3;           // staging: dh quad 0..3
  const int koff = 64 + h * 16 + sd * 4;
  const int voff = 128 + h * 16 + sd * 4;

  for (int mc = 0; mc < N_NODES; mc += 64) {
    // ---- stage 64 keys of K and V (V transposed) ----
    {
      const size_t rowb = (size_t)(mc + skey) * 192;
      float4 kv = *reinterpret_cast<const float4*>(qkv + rowb + koff);
      float4 vv = *reinterpret_cast<const float4*>(qkv + rowb + voff);
      short4 ks4 = make_short4(f2bf(kv.x), f2bf(kv.y), f2bf(kv.z), f2bf(kv.w));
      *reinterpret_cast<short4*>(&Ks[skey][sd * 4]) = ks4;
      Vt[sd * 4 + 0][skey] = f2bf(vv.x);
      Vt[sd * 4 + 1][skey] = f2bf(vv.y);
      Vt[sd * 4 + 2][skey] = f2bf(vv.z);
      Vt[sd * 4 + 3][skey] = f2bf(vv.w);
    }
    __syncthreads();

    // ---- scores: 4 sub-chunks of 16 keys ----
    f32x4 s[4];
    #pragma unroll
    for (int sub = 0; sub < 4; ++sub) {
      bf16x8 kf = {0, 0, 0, 0, 0, 0, 0, 0};
      if (lg < 2) kf = *reinterpret_cast<const bf16x8*>(&Ks[sub * 16 + lc][lg * 8]);
      f32x4 z = {0.f, 0.f, 0.f, 0.f};
      s[sub] = __builtin_amdgcn_mfma_f32_16x16x32_bf16(qfrag, kf, z, 0, 0, 0);
    }

    // ---- softmax weights -> P (LDS), fp32 row-sum ----
    #pragma unroll
    for (int sub = 0; sub < 4; ++sub) {
      #pragma unroll
      for (int r = 0; r < 4; ++r) {
        float w = __expf(s[sub][r]);
        wsum[r] += w;
        Ps[wv][lg * 4 + r][sub * 16 + lc] = f2bf(w);
      }
    }
    // drain LDS writes before cross-lane reads (same wave)
    asm volatile("s_waitcnt lgkmcnt(0)" ::: "memory");

    // ---- PV: out[16q x 16dh] += P[16 x 64] * V[64 x 16] ----
    #pragma unroll
    for (int half = 0; half < 2; ++half) {
      bf16x8 pf = *reinterpret_cast<const bf16x8*>(&Ps[wv][lc][half * 32 + lg * 8]);
      bf16x8 vf = *reinterpret_cast<const bf16x8*>(&Vt[lc][half * 32 + lg * 8]);
      oacc = __builtin_amdgcn_mfma_f32_16x16x32_bf16(pf, vf, oacc, 0, 0, 0);
    }
    __syncthreads();
  }

  // ---- reduce wsum across the 16 lanes holding each q-row's columns ----
  #pragma unroll
  for (int r = 0; r < 4; ++r) {
    float wsr = wsum[r];
    wsr += __shfl_xor(wsr, 1);
    wsr += __shfl_xor(wsr, 2);
    wsr += __shfl_xor(wsr, 4);
    wsr += __shfl_xor(wsr, 8);
    wsum[r] = wsr;
  }

  const int nbase = qb * 64 + wv * 16;
  #pragma unroll
  for (int r = 0; r < 4; ++r) {
    float v = oacc[r] / wsum[r];
    attn_out[(size_t)(nbase + lg * 4 + r) * 64 + h * 16 + lc] = v;
  }
}

// ---------------- GCN aggregation ----------------

template <int C, bool RELU>
__global__ __launch_bounds__(256) void aggregate(const float* __restrict__ hw,
                                                 const int* __restrict__ csr,
                                                 const int* __restrict__ row_off,
                                                 const int* __restrict__ deg,
                                                 const float* __restrict__ dinv,
                                                 const float* __restrict__ bias,
                                                 float* __restrict__ out) {
  const int w = threadIdx.x >> 6, l = threadIdx.x & 63;
  const int r = blockIdx.x * 4 + w;
  const float dr = dinv[r];
  const int off = row_off[r];
  const int cnt = deg[r] - 1;

  if constexpr (C == 256) {
    const int c = l << 2;
    float4 a = *reinterpret_cast<const float4*>(hw + (size_t)r * C + c);
    float ax = dr * a.x, ay = dr * a.y, az = dr * a.z, aw = dr * a.w;
    for (int e = 0; e < cnt; ++e) {
      int s = csr[off + e];
      float ws = dinv[s];
      float4 hv = *reinterpret_cast<const float4*>(hw + (size_t)s * C + c);
      ax += ws * hv.x; ay += ws * hv.y; az += ws * hv.z; aw += ws * hv.w;
    }
    float4 bv = *reinterpret_cast<const float4*>(bias + c);
    float4 o;
    o.x = dr * ax + bv.x; o.y = dr * ay + bv.y;
    o.z = dr * az + bv.z; o.w = dr * aw + bv.w;
    if (RELU) {
      o.x = fmaxf(o.x, 0.f); o.y = fmaxf(o.y, 0.f);
      o.z = fmaxf(o.z, 0.f); o.w = fmaxf(o.w, 0.f);
    }
    *reinterpret_cast<float4*>(out + (size_t)r * C + c) = o;
  } else {
    float a = dr * hw[(size_t)r * C + l];
    for (int e = 0; e < cnt; ++e) {
      int s = csr[off + e];
      a += dinv[s] * hw[(size_t)s * C + l];
    }
    float o = dr * a + bias[l];
    if (RELU) o = fmaxf(o, 0.f);
    out[(size_t)r * C + l] = o;
  }
}

// ---------------- launch ----------------

extern "C" void kernel_launch(void* const* d_in, const int* in_sizes, int n_in,
                              void* d_out, int out_size, void* d_ws, size_t ws_size,
                              hipStream_t stream) {
  const float* x          = (const float*)d_in[0];
  const int*   ei         = (const int*)d_in[1];
  const float* pe_w       = (const float*)d_in[2];
  const float* pe_b       = (const float*)d_in[3];
  const float* in_proj_w  = (const float*)d_in[4];
  const float* in_proj_b  = (const float*)d_in[5];
  const float* out_proj_w = (const float*)d_in[6];
  const float* out_proj_b = (const float*)d_in[7];
  const float* w1         = (const float*)d_in[8];
  const float* b1         = (const float*)d_in[9];
  const float* w2         = (const float*)d_in[10];
  const float* b2         = (const float*)d_in[11];
  const float* w3         = (const float*)d_in[12];
  const float* b3         = (const float*)d_in[13];

  const int* esrc = ei;
  const int* edst = ei + N_EDGES;

  char* ws = (char*)d_ws;
  size_t o = 0;
  auto take = [&](size_t n) {
    char* p = ws + o;
    o += (n + 255) & ~(size_t)255;
    return p;
  };
  float* pf       = (float*)take((size_t)N_NODES * PATH_DIM * 4);
  float* qkv      = (float*)take((size_t)N_NODES * 3 * PATH_DIM * 4);
  float* attn_out = (float*)take((size_t)N_NODES * PATH_DIM * 4);
  float* pa       = (float*)take((size_t)N_NODES * PATH_DIM * 4);
  float* hw       = (float*)take((size_t)N_NODES * HID * 4);
  float* h1       = (float*)take((size_t)N_NODES * HID * 4);
  float* h2       = (float*)take((size_t)N_NODES * HID * 4);
  float* Wt_in    = (float*)take((size_t)3 * PATH_DIM * PATH_DIM * 4);
  float* Wt_out   = (float*)take((size_t)PATH_DIM * PATH_DIM * 4);
  float* dinv     = (float*)take((size_t)N_NODES * 4);
  int*   deg      = (int*)take((size_t)N_NODES * 4);
  int*   cursor   = (int*)take((size_t)N_NODES * 4);
  int*   row_off  = (int*)take((size_t)N_NODES * 4);
  int*   csr      = (int*)take((size_t)N_EDGES * 4);

  init_graph<<<N_NODES / 256, 256, 0, stream>>>(deg, cursor);
  count_deg<<<N_EDGES / 256, 256, 0, stream>>>(edst, deg);
  scan_rows<<<1, 256, 0, stream>>>(deg, row_off, dinv);
  fill_csr<<<N_EDGES / 256, 256, 0, stream>>>(esrc, edst, row_off, cursor, csr);

  transpose_w<<<(192 * 64 + 255) / 256, 256, 0, stream>>>(in_proj_w, Wt_in, 192, 64);
  transpose_w<<<(64 * 64 + 255) / 256, 256, 0, stream>>>(out_proj_w, Wt_out, 64, 64);

  gemm_tile<false, true><<<dim3(1, 128), 256, 0, stream>>>(x, IN_DIM, nullptr, 0, pe_w, pe_b, pf, PATH_DIM);
  gemm_tile<false, true><<<dim3(3, 128), 256, 0, stream>>>(pf, PATH_DIM, nullptr, 0, Wt_in, in_proj_b, qkv, 3 * PATH_DIM);

  attn_mfma<<<dim3(128, 4), 256, 0, stream>>>(qkv, attn_out);

  gemm_tile<false, true><<<dim3(1, 128), 256, 0, stream>>>(attn_out, PATH_DIM, nullptr, 0, Wt_out, out_proj_b, pa, PATH_DIM);

  gemm_tile<false, false><<<dim3(4, 128), 256, 0, stream>>>(x, IN_DIM, pa, PATH_DIM, w1, nullptr, hw, HID);
  aggregate<256, true><<<N_NODES / 4, 256, 0, stream>>>(hw, csr, row_off, deg, dinv, b1, h1);
  gemm_tile<false, false><<<dim3(4, 128), 256, 0, stream>>>(h1, HID, nullptr, 0, w2, nullptr, hw, HID);
  aggregate<256, true><<<N_NODES / 4, 256, 0, stream>>>(hw, csr, row_off, deg, dinv, b2, h2);
  gemm_tile<false, false><<<dim3(1, 128), 256, 0, stream>>>(h2, HID, nullptr, 0, w3, nullptr, hw, OUT_DIM);
  aggregate<64, false><<<N_NODES / 4, 256, 0, stream>>>(hw, csr, row_off, deg, dinv, b3, (float*)d_out);
}

// Round 3
// 328.059 us; speedup vs baseline: 4.5657x; 1.1483x over previous
//
#include <hip/hip_runtime.h>
#include <hip/hip_bf16.h>

#define N_NODES 8192
#define N_EDGES 262144
#define IN_DIM 256
#define HID 256
#define OUT_DIM 64
#define PATH_DIM 64
#define NHEADS 4
#define DH 16

typedef __attribute__((ext_vector_type(8))) short bf16x8;
typedef __attribute__((ext_vector_type(4))) float f32x4;

__device__ __forceinline__ ushort f2bf(float f) {
  union { float f; unsigned int u; } c;
  c.f = f;
  unsigned int u = c.u;
  u += 0x7fffu + ((u >> 16) & 1u);
  return (ushort)(u >> 16);
}

__device__ __forceinline__ float fast_exp2(float x) {
  float r;
  asm("v_exp_f32 %0, %1" : "=v"(r) : "v"(x));
  return r;
}

__device__ __forceinline__ unsigned pack_bf16(float a, float b) {
  union { __hip_bfloat162 h; unsigned u; } c;
  c.h = __float22bfloat162_rn(make_float2(a, b));
  return c.u;
}

// ---------------- graph setup ----------------

__global__ __launch_bounds__(256) void init_graph(int* deg, int* cursor) {
  int i = blockIdx.x * 256 + threadIdx.x;
  if (i < N_NODES) { deg[i] = 1; cursor[i] = 0; }   // deg starts at 1 (self loop)
}

__global__ __launch_bounds__(256) void count_deg(const int* __restrict__ dst,
                                                 int* __restrict__ deg) {
  int e = blockIdx.x * 256 + threadIdx.x;
  if (e < N_EDGES) atomicAdd(&deg[dst[e]], 1);
}

__global__ __launch_bounds__(256) void scan_rows(const int* __restrict__ deg,
                                                 int* __restrict__ row_off,
                                                 float* __restrict__ dinv) {
  __shared__ int part[256];
  int t = threadIdx.x;
  int base = t * 32;
  int local[32];
  int s = 0;
  #pragma unroll
  for (int i = 0; i < 32; ++i) {
    int c = deg[base + i] - 1;
    local[i] = s;
    s += c;
  }
  part[t] = s;
  __syncthreads();
  for (int d = 1; d < 256; d <<= 1) {
    int v = (t >= d) ? part[t - d] : 0;
    __syncthreads();
    part[t] += v;
    __syncthreads();
  }
  int prev = (t == 0) ? 0 : part[t - 1];
  #pragma unroll
  for (int i = 0; i < 32; ++i) {
    row_off[base + i] = prev + local[i];
    dinv[base + i] = rsqrtf((float)deg[base + i]);
  }
}

__global__ __launch_bounds__(256) void fill_csr(const int* __restrict__ src,
                                                const int* __restrict__ dst,
                                                const int* __restrict__ row_off,
                                                int* __restrict__ cursor,
                                                int* __restrict__ csr) {
  int e = blockIdx.x * 256 + threadIdx.x;
  if (e < N_EDGES) {
    int d = dst[e];
    int p = atomicAdd(&cursor[d], 1);
    csr[row_off[d] + p] = src[e];
  }
}

// ---------------- small utility ----------------

__global__ __launch_bounds__(256) void transpose_w(const float* __restrict__ W,
                                                   float* __restrict__ Wt,
                                                   int R, int C) {
  int i = blockIdx.x * 256 + threadIdx.x;
  if (i < R * C) {
    int r = i / C, c = i % C;
    Wt[c * R + r] = W[i];
  }
}

// qkv f32 [8192][192] -> Qbf [4][8192][32] (x0.25*log2e, upper 16 zero),
//                        Kbf [4][8192][32] (upper 16 zero),
//                        Vtb [4][16][8192]
__global__ __launch_bounds__(256) void convert_qkv(const float* __restrict__ qkv,
                                                   ushort* __restrict__ Qbf,
                                                   ushort* __restrict__ Kbf,
                                                   ushort* __restrict__ Vtb) {
  const int tg = blockIdx.x * 256 + threadIdx.x;  // 0..32767
  const int h = tg >> 13;
  const int n = tg & 8191;
  const float SC = 0.36067376022224085f;  // 0.25 * log2(e)
  const float* base = qkv + (size_t)n * 192 + h * 16;
  ushort* qd = Qbf + ((size_t)h * 8192 + n) * 32;
  ushort* kd = Kbf + ((size_t)h * 8192 + n) * 32;
  ushort4 zz = make_ushort4(0, 0, 0, 0);
  #pragma unroll
  for (int i = 0; i < 16; i += 4) {
    float4 q4 = *reinterpret_cast<const float4*>(base + i);
    float4 k4 = *reinterpret_cast<const float4*>(base + 64 + i);
    float4 v4 = *reinterpret_cast<const float4*>(base + 128 + i);
    *reinterpret_cast<ushort4*>(qd + i) =
        make_ushort4(f2bf(q4.x * SC), f2bf(q4.y * SC), f2bf(q4.z * SC), f2bf(q4.w * SC));
    *reinterpret_cast<ushort4*>(kd + i) =
        make_ushort4(f2bf(k4.x), f2bf(k4.y), f2bf(k4.z), f2bf(k4.w));
    *reinterpret_cast<ushort4*>(qd + 16 + i) = zz;
    *reinterpret_cast<ushort4*>(kd + 16 + i) = zz;
    Vtb[((size_t)h * 16 + i + 0) * 8192 + n] = f2bf(v4.x);
    Vtb[((size_t)h * 16 + i + 1) * 8192 + n] = f2bf(v4.y);
    Vtb[((size_t)h * 16 + i + 2) * 8192 + n] = f2bf(v4.z);
    Vtb[((size_t)h * 16 + i + 3) * 8192 + n] = f2bf(v4.w);
  }
}

// ---------------- fp32 GEMM (64x64 tile) ----------------

template <bool RELU, bool BIAS>
__global__ __launch_bounds__(256) void gemm_tile(const float* __restrict__ A1, int K1,
                                                 const float* __restrict__ A2, int K2,
                                                 const float* __restrict__ B,
                                                 const float* __restrict__ bias,
                                                 float* __restrict__ C, int N) {
  __shared__ __align__(16) float As[16][64];
  __shared__ __align__(16) float Bs[16][68];
  const int K = K1 + K2;
  const int bm = blockIdx.y * 64;
  const int bn = blockIdx.x * 64;
  const int t = threadIdx.x;
  const int tx = t & 15, ty = t >> 4;
  const int am = t >> 2;
  const int ak = (t & 3) << 2;
  const int bk = t >> 4;
  const int bn4 = (t & 15) << 2;
  float acc[4][4] = {};
  for (int k0 = 0; k0 < K; k0 += 16) {
    int kk = k0 + ak;
    int row = bm + am;
    float4 av;
    if (kk < K1)
      av = *reinterpret_cast<const float4*>(A1 + (size_t)row * K1 + kk);
    else
      av = *reinterpret_cast<const float4*>(A2 + (size_t)row * K2 + (kk - K1));
    As[ak + 0][am] = av.x;
    As[ak + 1][am] = av.y;
    As[ak + 2][am] = av.z;
    As[ak + 3][am] = av.w;
    float4 bv = *reinterpret_cast<const float4*>(B + (size_t)(k0 + bk) * N + bn + bn4);
    *reinterpret_cast<float4*>(&Bs[bk][bn4]) = bv;
    __syncthreads();
    #pragma unroll
    for (int k = 0; k < 16; ++k) {
      float4 a = *reinterpret_cast<const float4*>(&As[k][ty << 2]);
      float4 b = *reinterpret_cast<const float4*>(&Bs[k][tx << 2]);
      acc[0][0] += a.x * b.x; acc[0][1] += a.x * b.y; acc[0][2] += a.x * b.z; acc[0][3] += a.x * b.w;
      acc[1][0] += a.y * b.x; acc[1][1] += a.y * b.y; acc[1][2] += a.y * b.z; acc[1][3] += a.y * b.w;
      acc[2][0] += a.z * b.x; acc[2][1] += a.z * b.y; acc[2][2] += a.z * b.z; acc[2][3] += a.z * b.w;
      acc[3][0] += a.w * b.x; acc[3][1] += a.w * b.y; acc[3][2] += a.w * b.z; acc[3][3] += a.w * b.w;
    }
    __syncthreads();
  }
  #pragma unroll
  for (int i = 0; i < 4; ++i) {
    int row = bm + (ty << 2) + i;
    float4 o = make_float4(acc[i][0], acc[i][1], acc[i][2], acc[i][3]);
    if (BIAS) {
      float4 bv = *reinterpret_cast<const float4*>(bias + bn + (tx << 2));
      o.x += bv.x; o.y += bv.y; o.z += bv.z; o.w += bv.w;
    }
    if (RELU) {
      o.x = fmaxf(o.x, 0.f); o.y = fmaxf(o.y, 0.f);
      o.z = fmaxf(o.z, 0.f); o.w = fmaxf(o.w, 0.f);
    }
    *reinterpret_cast<float4*>(C + (size_t)row * N + bn + (tx << 2)) = o;
  }
}

// ---------------- MFMA flash attention v2 ----------------
// grid (128 qblocks, 4 heads) x 256 threads (4 waves).
// Block covers 64 q-rows; wave w owns key strip [mc + w*16, mc + w*16 + 16).
// QK^T swapped: mfma(A=K, B=Q) -> C[key][q]; lane holds 4 consecutive key-cols
// of one q-col  -> P written as b64 (cvt_pk packed), XOR-swizzled.
// PV: mfma(A=P, B=V^T) over the full 64-key chunk, V triple-buffered in LDS.
// Softmax denominator: per-lane partials, reduced once in the epilogue.

__global__ __launch_bounds__(256) void attn_mfma2(const ushort* __restrict__ Qbf,
                                                  const ushort* __restrict__ Kbf,
                                                  const ushort* __restrict__ Vtb,
                                                  float* __restrict__ attn_out) {
  const int h  = blockIdx.y;
  const int qb = blockIdx.x;
  const int t  = threadIdx.x;
  const int wv = t >> 6;
  const int l  = t & 63;
  const int lg = l >> 4;
  const int lc = l & 15;

  __shared__ __align__(16) ushort Ps[2][64][64];   // 16 KB, 16B-granule swizzled
  __shared__ __align__(16) ushort Vls[3][16][64];  // 6 KB,  16B-granule swizzled
  __shared__ float wred[4][64];

  // ---- Q fragments (held for whole kernel; upper-K zeros stored in Qbf) ----
  bf16x8 qf[4];
  {
    const ushort* qbase = Qbf + ((size_t)h * 8192 + qb * 64) * 32;
    #pragma unroll
    for (int qt = 0; qt < 4; ++qt)
      qf[qt] = *reinterpret_cast<const bf16x8*>(qbase + (qt * 16 + lc) * 32 + lg * 8);
  }

  const ushort* kbase = Kbf + (size_t)h * 8192 * 32 + (wv * 16 + lc) * 32 + lg * 8;

  // ---- V staging addresses (each thread moves 8B per chunk) ----
  const int vrow = t >> 4;    // dh row 0..15
  const int vcol8 = t & 15;   // 8B unit within 128B row
  const ushort* vsrc = Vtb + ((size_t)h * 16 + vrow) * 8192 + vcol8 * 4;
  const int vdst = vrow * 128 + (((vcol8 >> 1) ^ (vrow & 7)) << 4) + (vcol8 & 1) * 8;

  // ---- P write/read byte offsets (swizzle: granule ^= row&7) ----
  const int pw_off = (((wv * 2 + (lg >> 1)) ^ (lc & 7)) << 4) + (lg & 1) * 8;  // + row*128
  int pr_off[2], vr_off[2];
  #pragma unroll
  for (int half = 0; half < 2; ++half) {
    int g = (half * 4 + lg) ^ (lc & 7);
    pr_off[half] = (wv * 16 + lc) * 128 + g * 16;
    vr_off[half] = lc * 128 + g * 16;
  }

  char* ps_base  = (char*)&Ps[0][0][0];
  char* vls_base = (char*)&Vls[0][0][0];

  // prologue: stage V chunk 0
  *reinterpret_cast<ushort4*>(vls_base + vdst) =
      *reinterpret_cast<const ushort4*>(vsrc);

  f32x4 oacc = {0.f, 0.f, 0.f, 0.f};
  float wsumP[4] = {0.f, 0.f, 0.f, 0.f};

  __syncthreads();

  for (int c = 0; c < 128; ++c) {
    const int mc = c * 64;
    // -- prefetch next V chunk into regs (T14 split: issue early, write late) --
    ushort4 vpre;
    const bool dopre = (c + 1 < 128);
    if (dopre) vpre = *reinterpret_cast<const ushort4*>(vsrc + mc + 64);

    // -- K fragment straight from global (L2-resident, coalesced) --
    bf16x8 kf = *reinterpret_cast<const bf16x8*>(kbase + (size_t)mc * 32);

    // -- QK^T swapped: C[key][q] --
    f32x4 s[4];
    #pragma unroll
    for (int qt = 0; qt < 4; ++qt) {
      f32x4 z = {0.f, 0.f, 0.f, 0.f};
      s[qt] = __builtin_amdgcn_mfma_f32_16x16x32_bf16(kf, qf[qt], z, 0, 0, 0);
    }

    // -- exp2, denominator partials, pack, swizzled b64 P-write --
    char* psb = ps_base + (c & 1) * 8192;
    #pragma unroll
    for (int qt = 0; qt < 4; ++qt) {
      float e0 = fast_exp2(s[qt][0]);
      float e1 = fast_exp2(s[qt][1]);
      float e2 = fast_exp2(s[qt][2]);
      float e3 = fast_exp2(s[qt][3]);
      wsumP[qt] += (e0 + e1) + (e2 + e3);
      uint2 pk;
      pk.x = pack_bf16(e0, e1);
      pk.y = pack_bf16(e2, e3);
      *reinterpret_cast<uint2*>(psb + (qt * 16 + lc) * 128 + pw_off) = pk;
    }

    // -- write prefetched V into buffer (c+1)%3 --
    if (dopre)
      *reinterpret_cast<ushort4*>(vls_base + ((c + 1) % 3) * 2048 + vdst) = vpre;

    __syncthreads();

    // -- PV: C[q][dh] += P[16q x 64k] * V[64k x 16dh] --
    char* vlb = vls_base + (c % 3) * 2048;
    #pragma unroll
    for (int half = 0; half < 2; ++half) {
      bf16x8 pf = *reinterpret_cast<const bf16x8*>(psb + pr_off[half]);
      bf16x8 vf = *reinterpret_cast<const bf16x8*>(vlb + vr_off[half]);
      oacc = __builtin_amdgcn_mfma_f32_16x16x32_bf16(pf, vf, oacc, 0, 0, 0);
    }
  }

  // ---- epilogue: denominator reduce (over lg within wave, then across waves) ----
  #pragma unroll
  for (int qt = 0; qt < 4; ++qt) {
    float v = wsumP[qt];
    v += __shfl_xor(v, 16);
    v += __shfl_xor(v, 32);
    wsumP[qt] = v;
  }
  if (lg == 0) {
    #pragma unroll
    for (int qt = 0; qt < 4; ++qt) wred[wv][qt * 16 + lc] = wsumP[qt];
  }
  __syncthreads();

  #pragma unroll
  for (int r = 0; r < 4; ++r) {
    const int qrow = wv * 16 + lg * 4 + r;
    float ws = wred[0][qrow] + wred[1][qrow] + wred[2][qrow] + wred[3][qrow];
    attn_out[(size_t)(qb * 64 + qrow) * 64 + h * 16 + lc] = oacc[r] / ws;
  }
}

// ---------------- GCN aggregation ----------------

template <int C, bool RELU>
__global__ __launch_bounds__(256) void aggregate(const float* __restrict__ hw,
                                                 const int* __restrict__ csr,
                                                 const int* __restrict__ row_off,
                                                 const int* __restrict__ deg,
                                                 const float* __restrict__ dinv,
                                                 const float* __restrict__ bias,
                                                 float* __restrict__ out) {
  const int w = threadIdx.x >> 6, l = threadIdx.x & 63;
  const int r = blockIdx.x * 4 + w;
  const float dr = dinv[r];
  const int off = row_off[r];
  const int cnt = deg[r] - 1;

  if constexpr (C == 256) {
    const int c = l << 2;
    float4 a = *reinterpret_cast<const float4*>(hw + (size_t)r * C + c);
    float ax = dr * a.x, ay = dr * a.y, az = dr * a.z, aw = dr * a.w;
    for (int e = 0; e < cnt; ++e) {
      int s = csr[off + e];
      float ws = dinv[s];
      float4 hv = *reinterpret_cast<const float4*>(hw + (size_t)s * C + c);
      ax += ws * hv.x; ay += ws * hv.y; az += ws * hv.z; aw += ws * hv.w;
    }
    float4 bv = *reinterpret_cast<const float4*>(bias + c);
    float4 o;
    o.x = dr * ax + bv.x; o.y = dr * ay + bv.y;
    o.z = dr * az + bv.z; o.w = dr * aw + bv.w;
    if (RELU) {
      o.x = fmaxf(o.x, 0.f); o.y = fmaxf(o.y, 0.f);
      o.z = fmaxf(o.z, 0.f); o.w = fmaxf(o.w, 0.f);
    }
    *reinterpret_cast<float4*>(out + (size_t)r * C + c) = o;
  } else {
    float a = dr * hw[(size_t)r * C + l];
    for (int e = 0; e < cnt; ++e) {
      int s = csr[off + e];
      a += dinv[s] * hw[(size_t)s * C + l];
    }
    float o = dr * a + bias[l];
    if (RELU) o = fmaxf(o, 0.f);
    out[(size_t)r * C + l] = o;
  }
}

// ---------------- launch ----------------

extern "C" void kernel_launch(void* const* d_in, const int* in_sizes, int n_in,
                              void* d_out, int out_size, void* d_ws, size_t ws_size,
                              hipStream_t stream) {
  const float* x          = (const float*)d_in[0];
  const int*   ei         = (const int*)d_in[1];
  const float* pe_w       = (const float*)d_in[2];
  const float* pe_b       = (const float*)d_in[3];
  const float* in_proj_w  = (const float*)d_in[4];
  const float* in_proj_b  = (const float*)d_in[5];
  const float* out_proj_w = (const float*)d_in[6];
  const float* out_proj_b = (const float*)d_in[7];
  const float* w1         = (const float*)d_in[8];
  const float* b1         = (const float*)d_in[9];
  const float* w2         = (const float*)d_in[10];
  const float* b2         = (const float*)d_in[11];
  const float* w3         = (const float*)d_in[12];
  const float* b3         = (const float*)d_in[13];

  const int* esrc = ei;
  const int* edst = ei + N_EDGES;

  char* ws = (char*)d_ws;
  size_t o = 0;
  auto take = [&](size_t n) {
    char* p = ws + o;
    o += (n + 255) & ~(size_t)255;
    return p;
  };
  float* pf       = (float*)take((size_t)N_NODES * PATH_DIM * 4);
  float* qkv      = (float*)take((size_t)N_NODES * 3 * PATH_DIM * 4);
  float* attn_out = (float*)take((size_t)N_NODES * PATH_DIM * 4);
  float* pa       = (float*)take((size_t)N_NODES * PATH_DIM * 4);
  float* hw       = (float*)take((size_t)N_NODES * HID * 4);
  float* h1       = (float*)take((size_t)N_NODES * HID * 4);
  float* h2       = (float*)take((size_t)N_NODES * HID * 4);
  float* Wt_in    = (float*)take((size_t)3 * PATH_DIM * PATH_DIM * 4);
  float* Wt_out   = (float*)take((size_t)PATH_DIM * PATH_DIM * 4);
  float* dinv     = (float*)take((size_t)N_NODES * 4);
  int*   deg      = (int*)take((size_t)N_NODES * 4);
  int*   cursor   = (int*)take((size_t)N_NODES * 4);
  int*   row_off  = (int*)take((size_t)N_NODES * 4);
  int*   csr      = (int*)take((size_t)N_EDGES * 4);

  // bf16 attention operand buffers, aliased into h1's region (h1 is written
  // only after attention completes; sizes: 2MB + 2MB + 1MB <= 8MB).
  ushort* Qbf = (ushort*)h1;
  ushort* Kbf = Qbf + (size_t)NHEADS * N_NODES * 32;
  ushort* Vtb = Kbf + (size_t)NHEADS * N_NODES * 32;

  init_graph<<<N_NODES / 256, 256, 0, stream>>>(deg, cursor);
  count_deg<<<N_EDGES / 256, 256, 0, stream>>>(edst, deg);
  scan_rows<<<1, 256, 0, stream>>>(deg, row_off, dinv);
  fill_csr<<<N_EDGES / 256, 256, 0, stream>>>(esrc, edst, row_off, cursor, csr);

  transpose_w<<<(192 * 64 + 255) / 256, 256, 0, stream>>>(in_proj_w, Wt_in, 192, 64);
  transpose_w<<<(64 * 64 + 255) / 256, 256, 0, stream>>>(out_proj_w, Wt_out, 64, 64);

  gemm_tile<false, true><<<dim3(1, 128), 256, 0, stream>>>(x, IN_DIM, nullptr, 0, pe_w, pe_b, pf, PATH_DIM);
  gemm_tile<false, true><<<dim3(3, 128), 256, 0, stream>>>(pf, PATH_DIM, nullptr, 0, Wt_in, in_proj_b, qkv, 3 * PATH_DIM);

  convert_qkv<<<(N_NODES * NHEADS) / 256, 256, 0, stream>>>(qkv, Qbf, Kbf, Vtb);
  attn_mfma2<<<dim3(128, 4), 256, 0, stream>>>(Qbf, Kbf, Vtb, attn_out);

  gemm_tile<false, true><<<dim3(1, 128), 256, 0, stream>>>(attn_out, PATH_DIM, nullptr, 0, Wt_out, out_proj_b, pa, PATH_DIM);

  gemm_tile<false, false><<<dim3(4, 128), 256, 0, stream>>>(x, IN_DIM, pa, PATH_DIM, w1, nullptr, hw, HID);
  aggregate<256, true><<<N_NODES / 4, 256, 0, stream>>>(hw, csr, row_off, deg, dinv, b1, h1);
  gemm_tile<false, false><<<dim3(4, 128), 256, 0, stream>>>(h1, HID, nullptr, 0, w2, nullptr, hw, HID);
  aggregate<256, true><<<N_NODES / 4, 256, 0, stream>>>(hw, csr, row_off, deg, dinv, b2, h2);
  gemm_tile<false, false><<<dim3(1, 128), 256, 0, stream>>>(h2, HID, nullptr, 0, w3, nullptr, hw, OUT_DIM);
  aggregate<64, false><<<N_NODES / 4, 256, 0, stream>>>(hw, csr, row_off, deg, dinv, b3, (float*)d_out);
}

// Round 4
// 304.012 us; speedup vs baseline: 4.9268x; 1.0791x over previous
//
#include <hip/hip_runtime.h>
#include <hip/hip_bf16.h>

#define N_NODES 8192
#define N_EDGES 262144
#define IN_DIM 256
#define HID 256
#define OUT_DIM 64
#define PATH_DIM 64
#define NHEADS 4
#define DH 16
#define KSPLIT 4

typedef __attribute__((ext_vector_type(8))) short bf16x8;
typedef __attribute__((ext_vector_type(4))) float f32x4;

__device__ __forceinline__ ushort f2bf(float f) {
  union { float f; unsigned int u; } c;
  c.f = f;
  unsigned int u = c.u;
  u += 0x7fffu + ((u >> 16) & 1u);
  return (ushort)(u >> 16);
}

__device__ __forceinline__ float fast_exp2(float x) {
  float r;
  asm("v_exp_f32 %0, %1" : "=v"(r) : "v"(x));
  return r;
}

__device__ __forceinline__ unsigned pack_bf16(float a, float b) {
  union { __hip_bfloat162 h; unsigned u; } c;
  c.h = __float22bfloat162_rn(make_float2(a, b));
  return c.u;
}

// ---------------- graph setup ----------------

__global__ __launch_bounds__(256) void init_graph(int* deg, int* cursor) {
  int i = blockIdx.x * 256 + threadIdx.x;
  if (i < N_NODES) { deg[i] = 1; cursor[i] = 0; }   // deg starts at 1 (self loop)
}

__global__ __launch_bounds__(256) void count_deg(const int* __restrict__ dst,
                                                 int* __restrict__ deg) {
  int e = blockIdx.x * 256 + threadIdx.x;
  if (e < N_EDGES) atomicAdd(&deg[dst[e]], 1);
}

__global__ __launch_bounds__(256) void scan_rows(const int* __restrict__ deg,
                                                 int* __restrict__ row_off,
                                                 float* __restrict__ dinv) {
  __shared__ int part[256];
  int t = threadIdx.x;
  int base = t * 32;
  int local[32];
  int s = 0;
  #pragma unroll
  for (int i = 0; i < 32; ++i) {
    int c = deg[base + i] - 1;
    local[i] = s;
    s += c;
  }
  part[t] = s;
  __syncthreads();
  for (int d = 1; d < 256; d <<= 1) {
    int v = (t >= d) ? part[t - d] : 0;
    __syncthreads();
    part[t] += v;
    __syncthreads();
  }
  int prev = (t == 0) ? 0 : part[t - 1];
  #pragma unroll
  for (int i = 0; i < 32; ++i) {
    row_off[base + i] = prev + local[i];
    dinv[base + i] = rsqrtf((float)deg[base + i]);
  }
}

__global__ __launch_bounds__(256) void fill_csr(const int* __restrict__ src,
                                                const int* __restrict__ dst,
                                                const int* __restrict__ row_off,
                                                int* __restrict__ cursor,
                                                int* __restrict__ csr) {
  int e = blockIdx.x * 256 + threadIdx.x;
  if (e < N_EDGES) {
    int d = dst[e];
    int p = atomicAdd(&cursor[d], 1);
    csr[row_off[d] + p] = src[e];
  }
}

// ---------------- small utility ----------------

__global__ __launch_bounds__(256) void transpose_w(const float* __restrict__ W,
                                                   float* __restrict__ Wt,
                                                   int R, int C) {
  int i = blockIdx.x * 256 + threadIdx.x;
  if (i < R * C) {
    int r = i / C, c = i % C;
    Wt[c * R + r] = W[i];
  }
}

// qkv f32 [8192][192] -> Qbf [4][8192][32] (x0.25*log2e, upper 16 zero),
//                        Kbf [4][8192][32] (upper 16 zero),
//                        Vtb [4][16][8192]
__global__ __launch_bounds__(256) void convert_qkv(const float* __restrict__ qkv,
                                                   ushort* __restrict__ Qbf,
                                                   ushort* __restrict__ Kbf,
                                                   ushort* __restrict__ Vtb) {
  const int tg = blockIdx.x * 256 + threadIdx.x;  // 0..32767
  const int h = tg >> 13;
  const int n = tg & 8191;
  const float SC = 0.36067376022224085f;  // 0.25 * log2(e)
  const float* base = qkv + (size_t)n * 192 + h * 16;
  ushort* qd = Qbf + ((size_t)h * 8192 + n) * 32;
  ushort* kd = Kbf + ((size_t)h * 8192 + n) * 32;
  ushort4 zz = make_ushort4(0, 0, 0, 0);
  #pragma unroll
  for (int i = 0; i < 16; i += 4) {
    float4 q4 = *reinterpret_cast<const float4*>(base + i);
    float4 k4 = *reinterpret_cast<const float4*>(base + 64 + i);
    float4 v4 = *reinterpret_cast<const float4*>(base + 128 + i);
    *reinterpret_cast<ushort4*>(qd + i) =
        make_ushort4(f2bf(q4.x * SC), f2bf(q4.y * SC), f2bf(q4.z * SC), f2bf(q4.w * SC));
    *reinterpret_cast<ushort4*>(kd + i) =
        make_ushort4(f2bf(k4.x), f2bf(k4.y), f2bf(k4.z), f2bf(k4.w));
    *reinterpret_cast<ushort4*>(qd + 16 + i) = zz;
    *reinterpret_cast<ushort4*>(kd + 16 + i) = zz;
    Vtb[((size_t)h * 16 + i + 0) * 8192 + n] = f2bf(v4.x);
    Vtb[((size_t)h * 16 + i + 1) * 8192 + n] = f2bf(v4.y);
    Vtb[((size_t)h * 16 + i + 2) * 8192 + n] = f2bf(v4.z);
    Vtb[((size_t)h * 16 + i + 3) * 8192 + n] = f2bf(v4.w);
  }
}

// ---------------- fp32 GEMM (64x64 tile) ----------------

template <bool RELU, bool BIAS>
__global__ __launch_bounds__(256) void gemm_tile(const float* __restrict__ A1, int K1,
                                                 const float* __restrict__ A2, int K2,
                                                 const float* __restrict__ B,
                                                 const float* __restrict__ bias,
                                                 float* __restrict__ C, int N) {
  __shared__ __align__(16) float As[16][64];
  __shared__ __align__(16) float Bs[16][68];
  const int K = K1 + K2;
  const int bm = blockIdx.y * 64;
  const int bn = blockIdx.x * 64;
  const int t = threadIdx.x;
  const int tx = t & 15, ty = t >> 4;
  const int am = t >> 2;
  const int ak = (t & 3) << 2;
  const int bk = t >> 4;
  const int bn4 = (t & 15) << 2;
  float acc[4][4] = {};
  for (int k0 = 0; k0 < K; k0 += 16) {
    int kk = k0 + ak;
    int row = bm + am;
    float4 av;
    if (kk < K1)
      av = *reinterpret_cast<const float4*>(A1 + (size_t)row * K1 + kk);
    else
      av = *reinterpret_cast<const float4*>(A2 + (size_t)row * K2 + (kk - K1));
    As[ak + 0][am] = av.x;
    As[ak + 1][am] = av.y;
    As[ak + 2][am] = av.z;
    As[ak + 3][am] = av.w;
    float4 bv = *reinterpret_cast<const float4*>(B + (size_t)(k0 + bk) * N + bn + bn4);
    *reinterpret_cast<float4*>(&Bs[bk][bn4]) = bv;
    __syncthreads();
    #pragma unroll
    for (int k = 0; k < 16; ++k) {
      float4 a = *reinterpret_cast<const float4*>(&As[k][ty << 2]);
      float4 b = *reinterpret_cast<const float4*>(&Bs[k][tx << 2]);
      acc[0][0] += a.x * b.x; acc[0][1] += a.x * b.y; acc[0][2] += a.x * b.z; acc[0][3] += a.x * b.w;
      acc[1][0] += a.y * b.x; acc[1][1] += a.y * b.y; acc[1][2] += a.y * b.z; acc[1][3] += a.y * b.w;
      acc[2][0] += a.z * b.x; acc[2][1] += a.z * b.y; acc[2][2] += a.z * b.z; acc[2][3] += a.z * b.w;
      acc[3][0] += a.w * b.x; acc[3][1] += a.w * b.y; acc[3][2] += a.w * b.z; acc[3][3] += a.w * b.w;
    }
    __syncthreads();
  }
  #pragma unroll
  for (int i = 0; i < 4; ++i) {
    int row = bm + (ty << 2) + i;
    float4 o = make_float4(acc[i][0], acc[i][1], acc[i][2], acc[i][3]);
    if (BIAS) {
      float4 bv = *reinterpret_cast<const float4*>(bias + bn + (tx << 2));
      o.x += bv.x; o.y += bv.y; o.z += bv.z; o.w += bv.w;
    }
    if (RELU) {
      o.x = fmaxf(o.x, 0.f); o.y = fmaxf(o.y, 0.f);
      o.z = fmaxf(o.z, 0.f); o.w = fmaxf(o.w, 0.f);
    }
    *reinterpret_cast<float4*>(C + (size_t)row * N + bn + (tx << 2)) = o;
  }
}

// ---------------- MFMA flash attention v3 (k-split) ----------------
// grid (128 qblocks, 4 heads, KSPLIT) x 256 threads (4 waves).
// Block covers 64 q-rows x 2048 keys; outputs UNNORMALIZED O-partial + wsum
// partial (no max subtraction -> partials are purely additive).

__global__ __launch_bounds__(256) void attn_mfma3(const ushort* __restrict__ Qbf,
                                                  const ushort* __restrict__ Kbf,
                                                  const ushort* __restrict__ Vtb,
                                                  float* __restrict__ Opart,
                                                  float* __restrict__ Wpart) {
  const int h  = blockIdx.y;
  const int qb = blockIdx.x;
  const int kz = blockIdx.z;
  const int t  = threadIdx.x;
  const int wv = t >> 6;
  const int l  = t & 63;
  const int lg = l >> 4;
  const int lc = l & 15;

  __shared__ __align__(16) ushort Ps[2][64][64];   // 16 KB, 16B-granule swizzled
  __shared__ __align__(16) ushort Vls[3][16][64];  // 6 KB,  16B-granule swizzled
  __shared__ float wred[4][64];

  // ---- Q fragments (upper-K zeros stored in Qbf) ----
  bf16x8 qf[4];
  {
    const ushort* qbase = Qbf + ((size_t)h * 8192 + qb * 64) * 32;
    #pragma unroll
    for (int qt = 0; qt < 4; ++qt)
      qf[qt] = *reinterpret_cast<const bf16x8*>(qbase + (qt * 16 + lc) * 32 + lg * 8);
  }

  const ushort* kbase =
      Kbf + (size_t)h * 8192 * 32 + ((size_t)kz * 2048 + wv * 16 + lc) * 32 + lg * 8;

  // ---- V staging addresses (each thread moves 8B per chunk) ----
  const int vrow = t >> 4;    // dh row 0..15
  const int vcol8 = t & 15;   // 8B unit within 128B row
  const ushort* vsrc = Vtb + ((size_t)h * 16 + vrow) * 8192 + kz * 2048 + vcol8 * 4;
  const int vdst = vrow * 128 + (((vcol8 >> 1) ^ (vrow & 7)) << 4) + (vcol8 & 1) * 8;

  // ---- P write/read byte offsets (swizzle: granule ^= row&7) ----
  const int pw_off = (((wv * 2 + (lg >> 1)) ^ (lc & 7)) << 4) + (lg & 1) * 8;  // + row*128
  int pr_off[2], vr_off[2];
  #pragma unroll
  for (int half = 0; half < 2; ++half) {
    int g = (half * 4 + lg) ^ (lc & 7);
    pr_off[half] = (wv * 16 + lc) * 128 + g * 16;
    vr_off[half] = lc * 128 + g * 16;
  }

  char* ps_base  = (char*)&Ps[0][0][0];
  char* vls_base = (char*)&Vls[0][0][0];

  // prologue: stage V chunk 0
  *reinterpret_cast<ushort4*>(vls_base + vdst) =
      *reinterpret_cast<const ushort4*>(vsrc);

  f32x4 oacc = {0.f, 0.f, 0.f, 0.f};
  float wsumP[4] = {0.f, 0.f, 0.f, 0.f};

  __syncthreads();

  for (int c = 0; c < 2048 / 64; ++c) {
    const int mc = c * 64;
    // -- prefetch next V chunk into regs (issue early, write late) --
    ushort4 vpre;
    const bool dopre = (c + 1 < 2048 / 64);
    if (dopre) vpre = *reinterpret_cast<const ushort4*>(vsrc + mc + 64);

    // -- K fragment straight from global (L2-resident, coalesced) --
    bf16x8 kf = *reinterpret_cast<const bf16x8*>(kbase + (size_t)mc * 32);

    // -- QK^T swapped: C[key][q] --
    f32x4 s[4];
    #pragma unroll
    for (int qt = 0; qt < 4; ++qt) {
      f32x4 z = {0.f, 0.f, 0.f, 0.f};
      s[qt] = __builtin_amdgcn_mfma_f32_16x16x32_bf16(kf, qf[qt], z, 0, 0, 0);
    }

    // -- exp2, denominator partials, pack, swizzled b64 P-write --
    char* psb = ps_base + (c & 1) * 8192;
    #pragma unroll
    for (int qt = 0; qt < 4; ++qt) {
      float e0 = fast_exp2(s[qt][0]);
      float e1 = fast_exp2(s[qt][1]);
      float e2 = fast_exp2(s[qt][2]);
      float e3 = fast_exp2(s[qt][3]);
      wsumP[qt] += (e0 + e1) + (e2 + e3);
      uint2 pk;
      pk.x = pack_bf16(e0, e1);
      pk.y = pack_bf16(e2, e3);
      *reinterpret_cast<uint2*>(psb + (qt * 16 + lc) * 128 + pw_off) = pk;
    }

    // -- write prefetched V into buffer (c+1)%3 --
    if (dopre)
      *reinterpret_cast<ushort4*>(vls_base + ((c + 1) % 3) * 2048 + vdst) = vpre;

    __syncthreads();

    // -- PV: C[q][dh] += P[16q x 64k] * V[64k x 16dh] --
    char* vlb = vls_base + (c % 3) * 2048;
    #pragma unroll
    for (int half = 0; half < 2; ++half) {
      bf16x8 pf = *reinterpret_cast<const bf16x8*>(psb + pr_off[half]);
      bf16x8 vf = *reinterpret_cast<const bf16x8*>(vlb + vr_off[half]);
      oacc = __builtin_amdgcn_mfma_f32_16x16x32_bf16(pf, vf, oacc, 0, 0, 0);
    }
  }

  // ---- epilogue: denominator partial reduce; write unnormalized partials ----
  #pragma unroll
  for (int qt = 0; qt < 4; ++qt) {
    float v = wsumP[qt];
    v += __shfl_xor(v, 16);
    v += __shfl_xor(v, 32);
    wsumP[qt] = v;
  }
  if (lg == 0) {
    #pragma unroll
    for (int qt = 0; qt < 4; ++qt) wred[wv][qt * 16 + lc] = wsumP[qt];
  }
  __syncthreads();

  const size_t obase = ((size_t)(kz * NHEADS + h) * N_NODES + qb * 64);
  #pragma unroll
  for (int r = 0; r < 4; ++r) {
    const int qrow = wv * 16 + lg * 4 + r;
    Opart[(obase + qrow) * 16 + lc] = oacc[r];
  }
  if (t < 64) {
    float ws = wred[0][t] + wred[1][t] + wred[2][t] + wred[3][t];
    Wpart[obase + t] = ws;
  }
}

// combine: attn_out[n][h*16+d] = sum_s Opart[s][h][n][d] / sum_s Wpart[s][h][n]
__global__ __launch_bounds__(256) void attn_combine(const float* __restrict__ Opart,
                                                    const float* __restrict__ Wpart,
                                                    float* __restrict__ attn_out) {
  int i = blockIdx.x * 256 + threadIdx.x;  // 0 .. 4*8192*4-1
  int dq = i & 3;
  int hn = i >> 2;
  int h = hn >> 13;
  int n = hn & 8191;
  float4 acc = make_float4(0.f, 0.f, 0.f, 0.f);
  float ws = 0.f;
  #pragma unroll
  for (int s = 0; s < KSPLIT; ++s) {
    const size_t row = ((size_t)(s * NHEADS + h) * N_NODES + n);
    float4 v = *reinterpret_cast<const float4*>(Opart + row * 16 + dq * 4);
    acc.x += v.x; acc.y += v.y; acc.z += v.z; acc.w += v.w;
    ws += Wpart[row];
  }
  float inv = 1.f / ws;
  float4 o = make_float4(acc.x * inv, acc.y * inv, acc.z * inv, acc.w * inv);
  *reinterpret_cast<float4*>(attn_out + (size_t)n * 64 + h * 16 + dq * 4) = o;
}

// ---------------- GCN aggregation ----------------

template <int C, bool RELU>
__global__ __launch_bounds__(256) void aggregate(const float* __restrict__ hw,
                                                 const int* __restrict__ csr,
                                                 const int* __restrict__ row_off,
                                                 const int* __restrict__ deg,
                                                 const float* __restrict__ dinv,
                                                 const float* __restrict__ bias,
                                                 float* __restrict__ out) {
  const int w = threadIdx.x >> 6, l = threadIdx.x & 63;
  const int r = blockIdx.x * 4 + w;
  const float dr = dinv[r];
  const int off = row_off[r];
  const int cnt = deg[r] - 1;

  if constexpr (C == 256) {
    const int c = l << 2;
    float4 a = *reinterpret_cast<const float4*>(hw + (size_t)r * C + c);
    float ax = dr * a.x, ay = dr * a.y, az = dr * a.z, aw = dr * a.w;
    for (int e = 0; e < cnt; ++e) {
      int s = csr[off + e];
      float ws = dinv[s];
      float4 hv = *reinterpret_cast<const float4*>(hw + (size_t)s * C + c);
      ax += ws * hv.x; ay += ws * hv.y; az += ws * hv.z; aw += ws * hv.w;
    }
    float4 bv = *reinterpret_cast<const float4*>(bias + c);
    float4 o;
    o.x = dr * ax + bv.x; o.y = dr * ay + bv.y;
    o.z = dr * az + bv.z; o.w = dr * aw + bv.w;
    if (RELU) {
      o.x = fmaxf(o.x, 0.f); o.y = fmaxf(o.y, 0.f);
      o.z = fmaxf(o.z, 0.f); o.w = fmaxf(o.w, 0.f);
    }
    *reinterpret_cast<float4*>(out + (size_t)r * C + c) = o;
  } else {
    float a = dr * hw[(size_t)r * C + l];
    for (int e = 0; e < cnt; ++e) {
      int s = csr[off + e];
      a += dinv[s] * hw[(size_t)s * C + l];
    }
    float o = dr * a + bias[l];
    if (RELU) o = fmaxf(o, 0.f);
    out[(size_t)r * C + l] = o;
  }
}

// ---------------- launch ----------------

extern "C" void kernel_launch(void* const* d_in, const int* in_sizes, int n_in,
                              void* d_out, int out_size, void* d_ws, size_t ws_size,
                              hipStream_t stream) {
  const float* x          = (const float*)d_in[0];
  const int*   ei         = (const int*)d_in[1];
  const float* pe_w       = (const float*)d_in[2];
  const float* pe_b       = (const float*)d_in[3];
  const float* in_proj_w  = (const float*)d_in[4];
  const float* in_proj_b  = (const float*)d_in[5];
  const float* out_proj_w = (const float*)d_in[6];
  const float* out_proj_b = (const float*)d_in[7];
  const float* w1         = (const float*)d_in[8];
  const float* b1         = (const float*)d_in[9];
  const float* w2         = (const float*)d_in[10];
  const float* b2         = (const float*)d_in[11];
  const float* w3         = (const float*)d_in[12];
  const float* b3         = (const float*)d_in[13];

  const int* esrc = ei;
  const int* edst = ei + N_EDGES;

  char* ws = (char*)d_ws;
  size_t o = 0;
  auto take = [&](size_t n) {
    char* p = ws + o;
    o += (n + 255) & ~(size_t)255;
    return p;
  };
  float* pf       = (float*)take((size_t)N_NODES * PATH_DIM * 4);
  float* qkv      = (float*)take((size_t)N_NODES * 3 * PATH_DIM * 4);
  float* attn_out = (float*)take((size_t)N_NODES * PATH_DIM * 4);
  float* pa       = (float*)take((size_t)N_NODES * PATH_DIM * 4);
  float* hw       = (float*)take((size_t)N_NODES * HID * 4);
  float* h1       = (float*)take((size_t)N_NODES * HID * 4);
  float* h2       = (float*)take((size_t)N_NODES * HID * 4);
  float* Wt_in    = (float*)take((size_t)3 * PATH_DIM * PATH_DIM * 4);
  float* Wt_out   = (float*)take((size_t)PATH_DIM * PATH_DIM * 4);
  float* dinv     = (float*)take((size_t)N_NODES * 4);
  int*   deg      = (int*)take((size_t)N_NODES * 4);
  int*   cursor   = (int*)take((size_t)N_NODES * 4);
  int*   row_off  = (int*)take((size_t)N_NODES * 4);
  int*   csr      = (int*)take((size_t)N_EDGES * 4);

  // bf16 attention operand buffers alias h1 (dead until layer-1 aggregate):
  // 2MB + 2MB + 1MB <= 8MB.
  ushort* Qbf = (ushort*)h1;
  ushort* Kbf = Qbf + (size_t)NHEADS * N_NODES * 32;
  ushort* Vtb = Kbf + (size_t)NHEADS * N_NODES * 32;
  // attention partials alias h2 (8MB, exact fit) and pa (512KB of 2MB):
  float* Opart = h2;   // [KSPLIT][NHEADS][N_NODES][16] f32 = 8MB
  float* Wpart = pa;   // [KSPLIT][NHEADS][N_NODES]     f32 = 512KB

  init_graph<<<N_NODES / 256, 256, 0, stream>>>(deg, cursor);
  count_deg<<<N_EDGES / 256, 256, 0, stream>>>(edst, deg);
  scan_rows<<<1, 256, 0, stream>>>(deg, row_off, dinv);
  fill_csr<<<N_EDGES / 256, 256, 0, stream>>>(esrc, edst, row_off, cursor, csr);

  transpose_w<<<(192 * 64 + 255) / 256, 256, 0, stream>>>(in_proj_w, Wt_in, 192, 64);
  transpose_w<<<(64 * 64 + 255) / 256, 256, 0, stream>>>(out_proj_w, Wt_out, 64, 64);

  gemm_tile<false, true><<<dim3(1, 128), 256, 0, stream>>>(x, IN_DIM, nullptr, 0, pe_w, pe_b, pf, PATH_DIM);
  gemm_tile<false, true><<<dim3(3, 128), 256, 0, stream>>>(pf, PATH_DIM, nullptr, 0, Wt_in, in_proj_b, qkv, 3 * PATH_DIM);

  convert_qkv<<<(N_NODES * NHEADS) / 256, 256, 0, stream>>>(qkv, Qbf, Kbf, Vtb);
  attn_mfma3<<<dim3(128, 4, KSPLIT), 256, 0, stream>>>(Qbf, Kbf, Vtb, Opart, Wpart);
  attn_combine<<<(NHEADS * N_NODES * 4) / 256, 256, 0, stream>>>(Opart, Wpart, attn_out);

  gemm_tile<false, true><<<dim3(1, 128), 256, 0, stream>>>(attn_out, PATH_DIM, nullptr, 0, Wt_out, out_proj_b, pa, PATH_DIM);

  gemm_tile<false, false><<<dim3(4, 128), 256, 0, stream>>>(x, IN_DIM, pa, PATH_DIM, w1, nullptr, hw, HID);
  aggregate<256, true><<<N_NODES / 4, 256, 0, stream>>>(hw, csr, row_off, deg, dinv, b1, h1);
  gemm_tile<false, false><<<dim3(4, 128), 256, 0, stream>>>(h1, HID, nullptr, 0, w2, nullptr, hw, HID);
  aggregate<256, true><<<N_NODES / 4, 256, 0, stream>>>(hw, csr, row_off, deg, dinv, b2, h2);
  gemm_tile<false, false><<<dim3(1, 128), 256, 0, stream>>>(h2, HID, nullptr, 0, w3, nullptr, hw, OUT_DIM);
  aggregate<64, false><<<N_NODES / 4, 256, 0, stream>>>(hw, csr, row_off, deg, dinv, b3, (float*)d_out);
}

// Round 5
// 296.682 us; speedup vs baseline: 5.0485x; 1.0247x over previous
//
#include <hip/hip_runtime.h>
#include <hip/hip_bf16.h>

#define N_NODES 8192
#define N_EDGES 262144
#define IN_DIM 256
#define HID 256
#define OUT_DIM 64
#define PATH_DIM 64
#define NHEADS 4
#define DH 16
#define KSPLIT 8
#define SPLIT_KEYS (N_NODES / KSPLIT)   // 1024
#define NCHUNK (SPLIT_KEYS / 64)        // 16

typedef __attribute__((ext_vector_type(8))) short bf16x8;
typedef __attribute__((ext_vector_type(4))) float f32x4;

__device__ __forceinline__ ushort f2bf(float f) {
  union { float f; unsigned int u; } c;
  c.f = f;
  unsigned int u = c.u;
  u += 0x7fffu + ((u >> 16) & 1u);
  return (ushort)(u >> 16);
}

__device__ __forceinline__ float fast_exp2(float x) {
  float r;
  asm("v_exp_f32 %0, %1" : "=v"(r) : "v"(x));
  return r;
}

__device__ __forceinline__ unsigned pack_bf16(float a, float b) {
  union { __hip_bfloat162 h; unsigned u; } c;
  c.h = __float22bfloat162_rn(make_float2(a, b));
  return c.u;
}

// ---------------- graph setup ----------------

__global__ __launch_bounds__(256) void init_graph(int* deg, int* cursor) {
  int i = blockIdx.x * 256 + threadIdx.x;
  if (i < N_NODES) { deg[i] = 1; cursor[i] = 0; }   // deg starts at 1 (self loop)
}

__global__ __launch_bounds__(256) void count_deg(const int* __restrict__ dst,
                                                 int* __restrict__ deg) {
  int e = blockIdx.x * 256 + threadIdx.x;
  if (e < N_EDGES) atomicAdd(&deg[dst[e]], 1);
}

__global__ __launch_bounds__(256) void scan_rows(const int* __restrict__ deg,
                                                 int* __restrict__ row_off,
                                                 float* __restrict__ dinv) {
  __shared__ int part[256];
  int t = threadIdx.x;
  int base = t * 32;
  int local[32];
  int s = 0;
  #pragma unroll
  for (int i = 0; i < 32; ++i) {
    int c = deg[base + i] - 1;
    local[i] = s;
    s += c;
  }
  part[t] = s;
  __syncthreads();
  for (int d = 1; d < 256; d <<= 1) {
    int v = (t >= d) ? part[t - d] : 0;
    __syncthreads();
    part[t] += v;
    __syncthreads();
  }
  int prev = (t == 0) ? 0 : part[t - 1];
  #pragma unroll
  for (int i = 0; i < 32; ++i) {
    row_off[base + i] = prev + local[i];
    dinv[base + i] = rsqrtf((float)deg[base + i]);
  }
}

__global__ __launch_bounds__(256) void fill_csr(const int* __restrict__ src,
                                                const int* __restrict__ dst,
                                                const int* __restrict__ row_off,
                                                int* __restrict__ cursor,
                                                int* __restrict__ csr) {
  int e = blockIdx.x * 256 + threadIdx.x;
  if (e < N_EDGES) {
    int d = dst[e];
    int p = atomicAdd(&cursor[d], 1);
    csr[row_off[d] + p] = src[e];
  }
}

// ---------------- small utility ----------------

__global__ __launch_bounds__(256) void transpose_w(const float* __restrict__ W,
                                                   float* __restrict__ Wt,
                                                   int R, int C) {
  int i = blockIdx.x * 256 + threadIdx.x;
  if (i < R * C) {
    int r = i / C, c = i % C;
    Wt[c * R + r] = W[i];
  }
}

// qkv f32 [8192][192] -> Qbf [4][8192][32] (x0.25*log2e, upper 16 zero),
//                        Kbf [4][8192][32] (upper 16 zero),
//                        Vtb [4][16][8192]
__global__ __launch_bounds__(256) void convert_qkv(const float* __restrict__ qkv,
                                                   ushort* __restrict__ Qbf,
                                                   ushort* __restrict__ Kbf,
                                                   ushort* __restrict__ Vtb) {
  const int tg = blockIdx.x * 256 + threadIdx.x;  // 0..32767
  const int h = tg >> 13;
  const int n = tg & 8191;
  const float SC = 0.36067376022224085f;  // 0.25 * log2(e)
  const float* base = qkv + (size_t)n * 192 + h * 16;
  ushort* qd = Qbf + ((size_t)h * 8192 + n) * 32;
  ushort* kd = Kbf + ((size_t)h * 8192 + n) * 32;
  ushort4 zz = make_ushort4(0, 0, 0, 0);
  #pragma unroll
  for (int i = 0; i < 16; i += 4) {
    float4 q4 = *reinterpret_cast<const float4*>(base + i);
    float4 k4 = *reinterpret_cast<const float4*>(base + 64 + i);
    float4 v4 = *reinterpret_cast<const float4*>(base + 128 + i);
    *reinterpret_cast<ushort4*>(qd + i) =
        make_ushort4(f2bf(q4.x * SC), f2bf(q4.y * SC), f2bf(q4.z * SC), f2bf(q4.w * SC));
    *reinterpret_cast<ushort4*>(kd + i) =
        make_ushort4(f2bf(k4.x), f2bf(k4.y), f2bf(k4.z), f2bf(k4.w));
    *reinterpret_cast<ushort4*>(qd + 16 + i) = zz;
    *reinterpret_cast<ushort4*>(kd + 16 + i) = zz;
    Vtb[((size_t)h * 16 + i + 0) * 8192 + n] = f2bf(v4.x);
    Vtb[((size_t)h * 16 + i + 1) * 8192 + n] = f2bf(v4.y);
    Vtb[((size_t)h * 16 + i + 2) * 8192 + n] = f2bf(v4.z);
    Vtb[((size_t)h * 16 + i + 3) * 8192 + n] = f2bf(v4.w);
  }
}

// ---------------- fp32 GEMM (64x64 tile) ----------------

template <bool RELU, bool BIAS>
__global__ __launch_bounds__(256) void gemm_tile(const float* __restrict__ A1, int K1,
                                                 const float* __restrict__ A2, int K2,
                                                 const float* __restrict__ B,
                                                 const float* __restrict__ bias,
                                                 float* __restrict__ C, int N) {
  __shared__ __align__(16) float As[16][64];
  __shared__ __align__(16) float Bs[16][68];
  const int K = K1 + K2;
  const int bm = blockIdx.y * 64;
  const int bn = blockIdx.x * 64;
  const int t = threadIdx.x;
  const int tx = t & 15, ty = t >> 4;
  const int am = t >> 2;
  const int ak = (t & 3) << 2;
  const int bk = t >> 4;
  const int bn4 = (t & 15) << 2;
  float acc[4][4] = {};
  for (int k0 = 0; k0 < K; k0 += 16) {
    int kk = k0 + ak;
    int row = bm + am;
    float4 av;
    if (kk < K1)
      av = *reinterpret_cast<const float4*>(A1 + (size_t)row * K1 + kk);
    else
      av = *reinterpret_cast<const float4*>(A2 + (size_t)row * K2 + (kk - K1));
    As[ak + 0][am] = av.x;
    As[ak + 1][am] = av.y;
    As[ak + 2][am] = av.z;
    As[ak + 3][am] = av.w;
    float4 bv = *reinterpret_cast<const float4*>(B + (size_t)(k0 + bk) * N + bn + bn4);
    *reinterpret_cast<float4*>(&Bs[bk][bn4]) = bv;
    __syncthreads();
    #pragma unroll
    for (int k = 0; k < 16; ++k) {
      float4 a = *reinterpret_cast<const float4*>(&As[k][ty << 2]);
      float4 b = *reinterpret_cast<const float4*>(&Bs[k][tx << 2]);
      acc[0][0] += a.x * b.x; acc[0][1] += a.x * b.y; acc[0][2] += a.x * b.z; acc[0][3] += a.x * b.w;
      acc[1][0] += a.y * b.x; acc[1][1] += a.y * b.y; acc[1][2] += a.y * b.z; acc[1][3] += a.y * b.w;
      acc[2][0] += a.z * b.x; acc[2][1] += a.z * b.y; acc[2][2] += a.z * b.z; acc[2][3] += a.z * b.w;
      acc[3][0] += a.w * b.x; acc[3][1] += a.w * b.y; acc[3][2] += a.w * b.z; acc[3][3] += a.w * b.w;
    }
    __syncthreads();
  }
  #pragma unroll
  for (int i = 0; i < 4; ++i) {
    int row = bm + (ty << 2) + i;
    float4 o = make_float4(acc[i][0], acc[i][1], acc[i][2], acc[i][3]);
    if (BIAS) {
      float4 bv = *reinterpret_cast<const float4*>(bias + bn + (tx << 2));
      o.x += bv.x; o.y += bv.y; o.z += bv.z; o.w += bv.w;
    }
    if (RELU) {
      o.x = fmaxf(o.x, 0.f); o.y = fmaxf(o.y, 0.f);
      o.z = fmaxf(o.z, 0.f); o.w = fmaxf(o.w, 0.f);
    }
    *reinterpret_cast<float4*>(C + (size_t)row * N + bn + (tx << 2)) = o;
  }
}

// ---------------- MFMA flash attention v4 (k-split 8, slim LDS) ----------------
// grid (128 qblocks, 4 heads, KSPLIT) x 256 threads (4 waves).
// Single P buffer + 2 barriers/chunk -> 13.3 KB LDS -> 8 blocks/CU (wave cap).
// K fragments prefetched one chunk ahead in regs; V double-buffered in LDS.

__global__ __launch_bounds__(256) void attn_mfma4(const ushort* __restrict__ Qbf,
                                                  const ushort* __restrict__ Kbf,
                                                  const ushort* __restrict__ Vtb,
                                                  float* __restrict__ Opart,
                                                  float* __restrict__ Wpart) {
  const int h  = blockIdx.y;
  const int qb = blockIdx.x;
  const int kz = blockIdx.z;
  const int t  = threadIdx.x;
  const int wv = t >> 6;
  const int l  = t & 63;
  const int lg = l >> 4;
  const int lc = l & 15;

  __shared__ __align__(16) ushort Ps[64][64];      // 8 KB, 16B-granule swizzled
  __shared__ __align__(16) ushort Vls[2][16][64];  // 4 KB, 16B-granule swizzled
  __shared__ float wred[4][64];

  // ---- Q fragments (upper-K zeros stored in Qbf) ----
  bf16x8 qf[4];
  {
    const ushort* qbase = Qbf + ((size_t)h * 8192 + qb * 64) * 32;
    #pragma unroll
    for (int qt = 0; qt < 4; ++qt)
      qf[qt] = *reinterpret_cast<const bf16x8*>(qbase + (qt * 16 + lc) * 32 + lg * 8);
  }

  const ushort* kbase =
      Kbf + (size_t)h * 8192 * 32 + ((size_t)kz * SPLIT_KEYS + wv * 16 + lc) * 32 + lg * 8;

  // ---- V staging addresses (each thread moves 8B per chunk) ----
  const int vrow = t >> 4;    // dh row 0..15
  const int vcol8 = t & 15;   // 8B unit within 128B row
  const ushort* vsrc = Vtb + ((size_t)h * 16 + vrow) * 8192 + kz * SPLIT_KEYS + vcol8 * 4;
  const int vdst = vrow * 128 + (((vcol8 >> 1) ^ (vrow & 7)) << 4) + (vcol8 & 1) * 8;

  // ---- P write/read byte offsets (swizzle: granule ^= row&7) ----
  const int pw_off = (((wv * 2 + (lg >> 1)) ^ (lc & 7)) << 4) + (lg & 1) * 8;  // + row*128
  int pr_off[2], vr_off[2];
  #pragma unroll
  for (int half = 0; half < 2; ++half) {
    int g = (half * 4 + lg) ^ (lc & 7);
    pr_off[half] = (wv * 16 + lc) * 128 + g * 16;
    vr_off[half] = lc * 128 + g * 16;
  }

  char* ps_base  = (char*)&Ps[0][0];
  char* vls_base = (char*)&Vls[0][0][0];

  // prologue: stage V chunk 0, prefetch K chunk 0
  *reinterpret_cast<ushort4*>(vls_base + vdst) =
      *reinterpret_cast<const ushort4*>(vsrc);
  bf16x8 kf = *reinterpret_cast<const bf16x8*>(kbase);

  f32x4 oacc = {0.f, 0.f, 0.f, 0.f};
  float wsumP[4] = {0.f, 0.f, 0.f, 0.f};

  __syncthreads();

  for (int c = 0; c < NCHUNK; ++c) {
    const bool more = (c + 1 < NCHUNK);
    // -- prefetch next V chunk + next K fragment into regs --
    ushort4 vpre;
    bf16x8 kf_n;
    if (more) {
      vpre = *reinterpret_cast<const ushort4*>(vsrc + (c + 1) * 64);
      kf_n = *reinterpret_cast<const bf16x8*>(kbase + (size_t)(c + 1) * 64 * 32);
    }

    // -- QK^T swapped: C[key][q] --
    f32x4 s[4];
    #pragma unroll
    for (int qt = 0; qt < 4; ++qt) {
      f32x4 z = {0.f, 0.f, 0.f, 0.f};
      s[qt] = __builtin_amdgcn_mfma_f32_16x16x32_bf16(kf, qf[qt], z, 0, 0, 0);
    }
    kf = kf_n;

    // -- exp2, denominator partials, pack, swizzled b64 P-write --
    #pragma unroll
    for (int qt = 0; qt < 4; ++qt) {
      float e0 = fast_exp2(s[qt][0]);
      float e1 = fast_exp2(s[qt][1]);
      float e2 = fast_exp2(s[qt][2]);
      float e3 = fast_exp2(s[qt][3]);
      wsumP[qt] += (e0 + e1) + (e2 + e3);
      uint2 pk;
      pk.x = pack_bf16(e0, e1);
      pk.y = pack_bf16(e2, e3);
      *reinterpret_cast<uint2*>(ps_base + (qt * 16 + lc) * 128 + pw_off) = pk;
    }

    // -- write prefetched V into buffer (c+1)&1 --
    if (more)
      *reinterpret_cast<ushort4*>(vls_base + ((c + 1) & 1) * 2048 + vdst) = vpre;

    __syncthreads();  // P + V(c+1) visible

    // -- PV: C[q][dh] += P[16q x 64k] * V[64k x 16dh] --
    char* vlb = vls_base + (c & 1) * 2048;
    #pragma unroll
    for (int half = 0; half < 2; ++half) {
      bf16x8 pf = *reinterpret_cast<const bf16x8*>(ps_base + pr_off[half]);
      bf16x8 vf = *reinterpret_cast<const bf16x8*>(vlb + vr_off[half]);
      oacc = __builtin_amdgcn_mfma_f32_16x16x32_bf16(pf, vf, oacc, 0, 0, 0);
    }

    __syncthreads();  // protect Ps (and V buf reuse) before next chunk's writes
  }

  // ---- epilogue: denominator partial reduce; write unnormalized partials ----
  #pragma unroll
  for (int qt = 0; qt < 4; ++qt) {
    float v = wsumP[qt];
    v += __shfl_xor(v, 16);
    v += __shfl_xor(v, 32);
    wsumP[qt] = v;
  }
  if (lg == 0) {
    #pragma unroll
    for (int qt = 0; qt < 4; ++qt) wred[wv][qt * 16 + lc] = wsumP[qt];
  }
  __syncthreads();

  const size_t obase = ((size_t)(kz * NHEADS + h) * N_NODES + qb * 64);
  #pragma unroll
  for (int r = 0; r < 4; ++r) {
    const int qrow = wv * 16 + lg * 4 + r;
    Opart[(obase + qrow) * 16 + lc] = oacc[r];
  }
  if (t < 64) {
    float ws = wred[0][t] + wred[1][t] + wred[2][t] + wred[3][t];
    Wpart[obase + t] = ws;
  }
}

// combine: attn_out[n][h*16+d] = sum_s Opart[s][h][n][d] / sum_s Wpart[s][h][n]
__global__ __launch_bounds__(256) void attn_combine(const float* __restrict__ Opart,
                                                    const float* __restrict__ Wpart,
                                                    float* __restrict__ attn_out) {
  int i = blockIdx.x * 256 + threadIdx.x;  // 0 .. 4*8192*4-1
  int dq = i & 3;
  int hn = i >> 2;
  int h = hn >> 13;
  int n = hn & 8191;
  float4 acc = make_float4(0.f, 0.f, 0.f, 0.f);
  float ws = 0.f;
  #pragma unroll
  for (int s = 0; s < KSPLIT; ++s) {
    const size_t row = ((size_t)(s * NHEADS + h) * N_NODES + n);
    float4 v = *reinterpret_cast<const float4*>(Opart + row * 16 + dq * 4);
    acc.x += v.x; acc.y += v.y; acc.z += v.z; acc.w += v.w;
    ws += Wpart[row];
  }
  float inv = 1.f / ws;
  float4 o = make_float4(acc.x * inv, acc.y * inv, acc.z * inv, acc.w * inv);
  *reinterpret_cast<float4*>(attn_out + (size_t)n * 64 + h * 16 + dq * 4) = o;
}

// ---------------- GCN aggregation ----------------
// C=256: 2 rows per block, 2 waves per row (even/odd edge split), LDS combine.

template <bool RELU>
__global__ __launch_bounds__(256) void aggregate2(const float* __restrict__ hw,
                                                  const int* __restrict__ csr,
                                                  const int* __restrict__ row_off,
                                                  const int* __restrict__ deg,
                                                  const float* __restrict__ dinv,
                                                  const float* __restrict__ bias,
                                                  float* __restrict__ out) {
  __shared__ __align__(16) float part[2][256];
  const int t = threadIdx.x;
  const int rw = t >> 7;          // row within block (0..1)
  const int wh = (t >> 6) & 1;    // wave half (even/odd edges)
  const int l = t & 63;
  const int r = blockIdx.x * 2 + rw;
  const float dr = dinv[r];
  const int off = row_off[r];
  const int cnt = deg[r] - 1;
  const int c = l << 2;

  float ax, ay, az, aw;
  if (wh == 0) {
    float4 a = *reinterpret_cast<const float4*>(hw + (size_t)r * 256 + c);
    ax = dr * a.x; ay = dr * a.y; az = dr * a.z; aw = dr * a.w;
  } else {
    ax = ay = az = aw = 0.f;
  }
  for (int e = wh; e < cnt; e += 2) {
    int s = csr[off + e];
    float wsc = dinv[s];
    float4 hv = *reinterpret_cast<const float4*>(hw + (size_t)s * 256 + c);
    ax += wsc * hv.x; ay += wsc * hv.y; az += wsc * hv.z; aw += wsc * hv.w;
  }
  if (wh == 1)
    *reinterpret_cast<float4*>(&part[rw][c]) = make_float4(ax, ay, az, aw);
  __syncthreads();
  if (wh == 0) {
    float4 p = *reinterpret_cast<const float4*>(&part[rw][c]);
    float4 bv = *reinterpret_cast<const float4*>(bias + c);
    float4 o;
    o.x = dr * (ax + p.x) + bv.x;
    o.y = dr * (ay + p.y) + bv.y;
    o.z = dr * (az + p.z) + bv.z;
    o.w = dr * (aw + p.w) + bv.w;
    if (RELU) {
      o.x = fmaxf(o.x, 0.f); o.y = fmaxf(o.y, 0.f);
      o.z = fmaxf(o.z, 0.f); o.w = fmaxf(o.w, 0.f);
    }
    *reinterpret_cast<float4*>(out + (size_t)r * 256 + c) = o;
  }
}

// C=64: one wave per row (layer 3, small)
template <bool RELU>
__global__ __launch_bounds__(256) void aggregate64(const float* __restrict__ hw,
                                                   const int* __restrict__ csr,
                                                   const int* __restrict__ row_off,
                                                   const int* __restrict__ deg,
                                                   const float* __restrict__ dinv,
                                                   const float* __restrict__ bias,
                                                   float* __restrict__ out) {
  const int w = threadIdx.x >> 6, l = threadIdx.x & 63;
  const int r = blockIdx.x * 4 + w;
  const float dr = dinv[r];
  const int off = row_off[r];
  const int cnt = deg[r] - 1;
  float a = dr * hw[(size_t)r * 64 + l];
  for (int e = 0; e < cnt; ++e) {
    int s = csr[off + e];
    a += dinv[s] * hw[(size_t)s * 64 + l];
  }
  float o = dr * a + bias[l];
  if (RELU) o = fmaxf(o, 0.f);
  out[(size_t)r * 64 + l] = o;
}

// ---------------- launch ----------------

extern "C" void kernel_launch(void* const* d_in, const int* in_sizes, int n_in,
                              void* d_out, int out_size, void* d_ws, size_t ws_size,
                              hipStream_t stream) {
  const float* x          = (const float*)d_in[0];
  const int*   ei         = (const int*)d_in[1];
  const float* pe_w       = (const float*)d_in[2];
  const float* pe_b       = (const float*)d_in[3];
  const float* in_proj_w  = (const float*)d_in[4];
  const float* in_proj_b  = (const float*)d_in[5];
  const float* out_proj_w = (const float*)d_in[6];
  const float* out_proj_b = (const float*)d_in[7];
  const float* w1         = (const float*)d_in[8];
  const float* b1         = (const float*)d_in[9];
  const float* w2         = (const float*)d_in[10];
  const float* b2         = (const float*)d_in[11];
  const float* w3         = (const float*)d_in[12];
  const float* b3         = (const float*)d_in[13];

  const int* esrc = ei;
  const int* edst = ei + N_EDGES;

  char* ws = (char*)d_ws;
  size_t o = 0;
  auto take = [&](size_t n) {
    char* p = ws + o;
    o += (n + 255) & ~(size_t)255;
    return p;
  };
  float* pf       = (float*)take((size_t)N_NODES * PATH_DIM * 4);
  float* qkv      = (float*)take((size_t)N_NODES * 3 * PATH_DIM * 4);
  float* attn_out = (float*)take((size_t)N_NODES * PATH_DIM * 4);
  float* pa       = (float*)take((size_t)N_NODES * PATH_DIM * 4);
  float* hw       = (float*)take((size_t)N_NODES * HID * 4);   // 8 MB
  float* h1       = (float*)take((size_t)N_NODES * HID * 4);   // 8 MB (right after hw)
  float* h2       = (float*)take((size_t)N_NODES * HID * 4);   // 8 MB
  float* Wt_in    = (float*)take((size_t)3 * PATH_DIM * PATH_DIM * 4);
  float* Wt_out   = (float*)take((size_t)PATH_DIM * PATH_DIM * 4);
  float* dinv     = (float*)take((size_t)N_NODES * 4);
  int*   deg      = (int*)take((size_t)N_NODES * 4);
  int*   cursor   = (int*)take((size_t)N_NODES * 4);
  int*   row_off  = (int*)take((size_t)N_NODES * 4);
  int*   csr      = (int*)take((size_t)N_EDGES * 4);

  // bf16 attention operands alias h2 (dead until layer-2 aggregate): 5 MB <= 8 MB.
  ushort* Qbf = (ushort*)h2;
  ushort* Kbf = Qbf + (size_t)NHEADS * N_NODES * 32;
  ushort* Vtb = Kbf + (size_t)NHEADS * N_NODES * 32;
  // attention partials: Opart spans hw..h1 (16 MB, contiguous, dead during attn);
  // Wpart aliases pa (1 MB of 2 MB).
  float* Opart = hw;   // [KSPLIT][NHEADS][N_NODES][16] f32 = 16 MB
  float* Wpart = pa;   // [KSPLIT][NHEADS][N_NODES]     f32 = 1 MB

  init_graph<<<N_NODES / 256, 256, 0, stream>>>(deg, cursor);
  count_deg<<<N_EDGES / 256, 256, 0, stream>>>(edst, deg);
  scan_rows<<<1, 256, 0, stream>>>(deg, row_off, dinv);
  fill_csr<<<N_EDGES / 256, 256, 0, stream>>>(esrc, edst, row_off, cursor, csr);

  transpose_w<<<(192 * 64 + 255) / 256, 256, 0, stream>>>(in_proj_w, Wt_in, 192, 64);
  transpose_w<<<(64 * 64 + 255) / 256, 256, 0, stream>>>(out_proj_w, Wt_out, 64, 64);

  gemm_tile<false, true><<<dim3(1, 128), 256, 0, stream>>>(x, IN_DIM, nullptr, 0, pe_w, pe_b, pf, PATH_DIM);
  gemm_tile<false, true><<<dim3(3, 128), 256, 0, stream>>>(pf, PATH_DIM, nullptr, 0, Wt_in, in_proj_b, qkv, 3 * PATH_DIM);

  convert_qkv<<<(N_NODES * NHEADS) / 256, 256, 0, stream>>>(qkv, Qbf, Kbf, Vtb);
  attn_mfma4<<<dim3(128, 4, KSPLIT), 256, 0, stream>>>(Qbf, Kbf, Vtb, Opart, Wpart);
  attn_combine<<<(NHEADS * N_NODES * 4) / 256, 256, 0, stream>>>(Opart, Wpart, attn_out);

  gemm_tile<false, true><<<dim3(1, 128), 256, 0, stream>>>(attn_out, PATH_DIM, nullptr, 0, Wt_out, out_proj_b, pa, PATH_DIM);

  gemm_tile<false, false><<<dim3(4, 128), 256, 0, stream>>>(x, IN_DIM, pa, PATH_DIM, w1, nullptr, hw, HID);
  aggregate2<true><<<N_NODES / 2, 256, 0, stream>>>(hw, csr, row_off, deg, dinv, b1, h1);
  gemm_tile<false, false><<<dim3(4, 128), 256, 0, stream>>>(h1, HID, nullptr, 0, w2, nullptr, hw, HID);
  aggregate2<true><<<N_NODES / 2, 256, 0, stream>>>(hw, csr, row_off, deg, dinv, b2, h2);
  gemm_tile<false, false><<<dim3(1, 128), 256, 0, stream>>>(h2, HID, nullptr, 0, w3, nullptr, hw, OUT_DIM);
  aggregate64<false><<<N_NODES / 4, 256, 0, stream>>>(hw, csr, row_off, deg, dinv, b3, (float*)d_out);
}

// Round 6
// 296.505 us; speedup vs baseline: 5.0515x; 1.0006x over previous
//
#include <hip/hip_runtime.h>
#include <hip/hip_bf16.h>

#define N_NODES 8192
#define N_EDGES 262144
#define IN_DIM 256
#define HID 256
#define OUT_DIM 64
#define PATH_DIM 64
#define NHEADS 4
#define DH 16
#define KSPLIT 8
#define SPLIT_KEYS (N_NODES / KSPLIT)   // 1024
#define NITER (SPLIT_KEYS / 64)         // 16 (wave strip: 16 keys/iter, 4 waves interleaved)

typedef __attribute__((ext_vector_type(8))) short bf16x8;
typedef __attribute__((ext_vector_type(4))) short bf16x4;
typedef __attribute__((ext_vector_type(4))) float f32x4;

__device__ __forceinline__ ushort f2bf(float f) {
  union { float f; unsigned int u; } c;
  c.f = f;
  unsigned int u = c.u;
  u += 0x7fffu + ((u >> 16) & 1u);
  return (ushort)(u >> 16);
}

__device__ __forceinline__ float fast_exp2(float x) {
  float r;
  asm("v_exp_f32 %0, %1" : "=v"(r) : "v"(x));
  return r;
}

__device__ __forceinline__ unsigned pack_bf16(float a, float b) {
  union { __hip_bfloat162 h; unsigned u; } c;
  c.h = __float22bfloat162_rn(make_float2(a, b));
  return c.u;
}

// PV matrix op: 16x16x16 bf16 (K=16). Instruction exists on gfx950 (ISA §10).
#if __has_builtin(__builtin_amdgcn_mfma_f32_16x16x16bf16_1k)
__device__ __forceinline__ f32x4 mfma16(bf16x4 a, bf16x4 b, f32x4 c) {
  return __builtin_amdgcn_mfma_f32_16x16x16bf16_1k(a, b, c, 0, 0, 0);
}
#else
__device__ __forceinline__ f32x4 mfma16(bf16x4 a, bf16x4 b, f32x4 c) {
  f32x4 d;
  asm volatile("v_mfma_f32_16x16x16_bf16 %0, %1, %2, %3\n\ts_nop 7\n\ts_nop 3"
               : "=v"(d) : "v"(a), "v"(b), "v"(c));
  return d;
}
#endif

// ---------------- graph setup ----------------

__global__ __launch_bounds__(256) void init_graph(int* deg, int* cursor) {
  int i = blockIdx.x * 256 + threadIdx.x;
  if (i < N_NODES) { deg[i] = 1; cursor[i] = 0; }   // deg starts at 1 (self loop)
}

__global__ __launch_bounds__(256) void count_deg(const int* __restrict__ dst,
                                                 int* __restrict__ deg) {
  int e = blockIdx.x * 256 + threadIdx.x;
  if (e < N_EDGES) atomicAdd(&deg[dst[e]], 1);
}

__global__ __launch_bounds__(256) void scan_rows(const int* __restrict__ deg,
                                                 int* __restrict__ row_off,
                                                 float* __restrict__ dinv) {
  __shared__ int part[256];
  int t = threadIdx.x;
  int base = t * 32;
  int local[32];
  int s = 0;
  #pragma unroll
  for (int i = 0; i < 32; ++i) {
    int c = deg[base + i] - 1;
    local[i] = s;
    s += c;
  }
  part[t] = s;
  __syncthreads();
  for (int d = 1; d < 256; d <<= 1) {
    int v = (t >= d) ? part[t - d] : 0;
    __syncthreads();
    part[t] += v;
    __syncthreads();
  }
  int prev = (t == 0) ? 0 : part[t - 1];
  #pragma unroll
  for (int i = 0; i < 32; ++i) {
    row_off[base + i] = prev + local[i];
    dinv[base + i] = rsqrtf((float)deg[base + i]);
  }
}

__global__ __launch_bounds__(256) void fill_csr(const int* __restrict__ src,
                                                const int* __restrict__ dst,
                                                const int* __restrict__ row_off,
                                                int* __restrict__ cursor,
                                                int* __restrict__ csr) {
  int e = blockIdx.x * 256 + threadIdx.x;
  if (e < N_EDGES) {
    int d = dst[e];
    int p = atomicAdd(&cursor[d], 1);
    csr[row_off[d] + p] = src[e];
  }
}

// ---------------- small utility ----------------

__global__ __launch_bounds__(256) void transpose_w(const float* __restrict__ W,
                                                   float* __restrict__ Wt,
                                                   int R, int C) {
  int i = blockIdx.x * 256 + threadIdx.x;
  if (i < R * C) {
    int r = i / C, c = i % C;
    Wt[c * R + r] = W[i];
  }
}

// qkv f32 [8192][192] -> Qbf [4][8192][32] (x0.25*log2e, upper 16 zero),
//                        Kbf [4][8192][32] (upper 16 zero),
//                        Vtb [4][16][8192]
__global__ __launch_bounds__(256) void convert_qkv(const float* __restrict__ qkv,
                                                   ushort* __restrict__ Qbf,
                                                   ushort* __restrict__ Kbf,
                                                   ushort* __restrict__ Vtb) {
  const int tg = blockIdx.x * 256 + threadIdx.x;  // 0..32767
  const int h = tg >> 13;
  const int n = tg & 8191;
  const float SC = 0.36067376022224085f;  // 0.25 * log2(e)
  const float* base = qkv + (size_t)n * 192 + h * 16;
  ushort* qd = Qbf + ((size_t)h * 8192 + n) * 32;
  ushort* kd = Kbf + ((size_t)h * 8192 + n) * 32;
  ushort4 zz = make_ushort4(0, 0, 0, 0);
  #pragma unroll
  for (int i = 0; i < 16; i += 4) {
    float4 q4 = *reinterpret_cast<const float4*>(base + i);
    float4 k4 = *reinterpret_cast<const float4*>(base + 64 + i);
    float4 v4 = *reinterpret_cast<const float4*>(base + 128 + i);
    *reinterpret_cast<ushort4*>(qd + i) =
        make_ushort4(f2bf(q4.x * SC), f2bf(q4.y * SC), f2bf(q4.z * SC), f2bf(q4.w * SC));
    *reinterpret_cast<ushort4*>(kd + i) =
        make_ushort4(f2bf(k4.x), f2bf(k4.y), f2bf(k4.z), f2bf(k4.w));
    *reinterpret_cast<ushort4*>(qd + 16 + i) = zz;
    *reinterpret_cast<ushort4*>(kd + 16 + i) = zz;
    Vtb[((size_t)h * 16 + i + 0) * 8192 + n] = f2bf(v4.x);
    Vtb[((size_t)h * 16 + i + 1) * 8192 + n] = f2bf(v4.y);
    Vtb[((size_t)h * 16 + i + 2) * 8192 + n] = f2bf(v4.z);
    Vtb[((size_t)h * 16 + i + 3) * 8192 + n] = f2bf(v4.w);
  }
}

// ---------------- fp32 GEMM (64x64 tile) ----------------

template <bool RELU, bool BIAS>
__global__ __launch_bounds__(256) void gemm_tile(const float* __restrict__ A1, int K1,
                                                 const float* __restrict__ A2, int K2,
                                                 const float* __restrict__ B,
                                                 const float* __restrict__ bias,
                                                 float* __restrict__ C, int N) {
  __shared__ __align__(16) float As[16][64];
  __shared__ __align__(16) float Bs[16][68];
  const int K = K1 + K2;
  const int bm = blockIdx.y * 64;
  const int bn = blockIdx.x * 64;
  const int t = threadIdx.x;
  const int tx = t & 15, ty = t >> 4;
  const int am = t >> 2;
  const int ak = (t & 3) << 2;
  const int bk = t >> 4;
  const int bn4 = (t & 15) << 2;
  float acc[4][4] = {};
  for (int k0 = 0; k0 < K; k0 += 16) {
    int kk = k0 + ak;
    int row = bm + am;
    float4 av;
    if (kk < K1)
      av = *reinterpret_cast<const float4*>(A1 + (size_t)row * K1 + kk);
    else
      av = *reinterpret_cast<const float4*>(A2 + (size_t)row * K2 + (kk - K1));
    As[ak + 0][am] = av.x;
    As[ak + 1][am] = av.y;
    As[ak + 2][am] = av.z;
    As[ak + 3][am] = av.w;
    float4 bv = *reinterpret_cast<const float4*>(B + (size_t)(k0 + bk) * N + bn + bn4);
    *reinterpret_cast<float4*>(&Bs[bk][bn4]) = bv;
    __syncthreads();
    #pragma unroll
    for (int k = 0; k < 16; ++k) {
      float4 a = *reinterpret_cast<const float4*>(&As[k][ty << 2]);
      float4 b = *reinterpret_cast<const float4*>(&Bs[k][tx << 2]);
      acc[0][0] += a.x * b.x; acc[0][1] += a.x * b.y; acc[0][2] += a.x * b.z; acc[0][3] += a.x * b.w;
      acc[1][0] += a.y * b.x; acc[1][1] += a.y * b.y; acc[1][2] += a.y * b.z; acc[1][3] += a.y * b.w;
      acc[2][0] += a.z * b.x; acc[2][1] += a.z * b.y; acc[2][2] += a.z * b.z; acc[2][3] += a.z * b.w;
      acc[3][0] += a.w * b.x; acc[3][1] += a.w * b.y; acc[3][2] += a.w * b.z; acc[3][3] += a.w * b.w;
    }
    __syncthreads();
  }
  #pragma unroll
  for (int i = 0; i < 4; ++i) {
    int row = bm + (ty << 2) + i;
    float4 o = make_float4(acc[i][0], acc[i][1], acc[i][2], acc[i][3]);
    if (BIAS) {
      float4 bv = *reinterpret_cast<const float4*>(bias + bn + (tx << 2));
      o.x += bv.x; o.y += bv.y; o.z += bv.z; o.w += bv.w;
    }
    if (RELU) {
      o.x = fmaxf(o.x, 0.f); o.y = fmaxf(o.y, 0.f);
      o.z = fmaxf(o.z, 0.f); o.w = fmaxf(o.w, 0.f);
    }
    *reinterpret_cast<float4*>(C + (size_t)row * N + bn + (tx << 2)) = o;
  }
}

// ---------------- MFMA flash attention v5 (in-register P, barrier-free) ----------------
// grid (128 qblocks, 4 heads, KSPLIT) x 256 threads (4 waves).
// Wave wv handles keys {kz*1024 + c*64 + wv*16 + 0..15}, c = 0..15, for all 64 q.
// QK^T swapped: mfma_16x16x32(A=K, B=Q) -> C[key][q]: lane holds q=lane&15,
// keys lg*4+r -- which is EXACTLY the A-fragment layout of mfma_16x16x16
// (row=lane&15, k=lg*4+j). So P = exp(C) stays in registers; PV B-frag (V^T)
// is a direct 8B global load. Zero LDS / zero barriers in the main loop;
// one epilogue barrier reduces O / denominator partials across the 4 waves.

__global__ __launch_bounds__(256) void attn_mfma5(const ushort* __restrict__ Qbf,
                                                  const ushort* __restrict__ Kbf,
                                                  const ushort* __restrict__ Vtb,
                                                  float* __restrict__ Opart,
                                                  float* __restrict__ Wpart) {
  const int h  = blockIdx.y;
  const int qb = blockIdx.x;
  const int kz = blockIdx.z;
  const int t  = threadIdx.x;
  const int wv = t >> 6;
  const int l  = t & 63;
  const int lg = l >> 4;
  const int lc = l & 15;

  __shared__ float red_o[3][64][17];
  __shared__ float red_w[3][64];

  // Q B-fragments (16x16x32): lane holds Q[q=lc][dh=lg*8..+7] (zeros for lg>=2)
  bf16x8 qf[4];
  {
    const ushort* qbase = Qbf + ((size_t)h * 8192 + qb * 64) * 32;
    #pragma unroll
    for (int qt = 0; qt < 4; ++qt)
      qf[qt] = *reinterpret_cast<const bf16x8*>(qbase + (qt * 16 + lc) * 32 + lg * 8);
  }

  // K A-fragment pointer: row=key=strip+lc, k=dh=lg*8+j
  const ushort* kptr =
      Kbf + ((size_t)h * 8192 + kz * SPLIT_KEYS + wv * 16 + lc) * 32 + lg * 8;
  // V^T B-fragment pointer (16x16x16): B[k=key=strip+lg*4+j][n=dh=lc]
  const ushort* vptr =
      Vtb + ((size_t)h * 16 + lc) * 8192 + kz * SPLIT_KEYS + wv * 16 + lg * 4;

  f32x4 oacc[4] = {{0.f, 0.f, 0.f, 0.f}, {0.f, 0.f, 0.f, 0.f},
                   {0.f, 0.f, 0.f, 0.f}, {0.f, 0.f, 0.f, 0.f}};
  float wsum[4] = {0.f, 0.f, 0.f, 0.f};

  bf16x8 kf = *reinterpret_cast<const bf16x8*>(kptr);
  bf16x4 vf = *reinterpret_cast<const bf16x4*>(vptr);

  for (int c = 0; c < NITER; ++c) {
    bf16x8 kf_n;
    bf16x4 vf_n;
    if (c + 1 < NITER) {
      kf_n = *reinterpret_cast<const bf16x8*>(kptr + (size_t)(c + 1) * 64 * 32);
      vf_n = *reinterpret_cast<const bf16x4*>(vptr + (size_t)(c + 1) * 64);
    }

    // QK^T: C[key(strip)][q] per 16-q tile
    f32x4 s[4];
    #pragma unroll
    for (int qt = 0; qt < 4; ++qt) {
      f32x4 z = {0.f, 0.f, 0.f, 0.f};
      s[qt] = __builtin_amdgcn_mfma_f32_16x16x32_bf16(kf, qf[qt], z, 0, 0, 0);
    }

    // exp2 -> in-register P fragment -> PV (16x16x16, K=16 keys)
    #pragma unroll
    for (int qt = 0; qt < 4; ++qt) {
      float e0 = fast_exp2(s[qt][0]);
      float e1 = fast_exp2(s[qt][1]);
      float e2 = fast_exp2(s[qt][2]);
      float e3 = fast_exp2(s[qt][3]);
      wsum[qt] += (e0 + e1) + (e2 + e3);
      uint2 pk;
      pk.x = pack_bf16(e0, e1);
      pk.y = pack_bf16(e2, e3);
      bf16x4 pf;
      pf[0] = (short)(pk.x & 0xffff); pf[1] = (short)(pk.x >> 16);
      pf[2] = (short)(pk.y & 0xffff); pf[3] = (short)(pk.y >> 16);
      oacc[qt] = mfma16(pf, vf, oacc[qt]);
    }

    kf = kf_n;
    vf = vf_n;
  }

  // ---- denominator: reduce over lg (keys within wave) ----
  #pragma unroll
  for (int qt = 0; qt < 4; ++qt) {
    float v = wsum[qt];
    v += __shfl_xor(v, 16);
    v += __shfl_xor(v, 32);
    wsum[qt] = v;   // strip total for q = qt*16 + lc
  }

  // ---- cross-wave reduce (single barrier) ----
  if (wv > 0) {
    #pragma unroll
    for (int qt = 0; qt < 4; ++qt) {
      #pragma unroll
      for (int r = 0; r < 4; ++r)
        red_o[wv - 1][qt * 16 + lg * 4 + r][lc] = oacc[qt][r];
      if (lg == 0) red_w[wv - 1][qt * 16 + lc] = wsum[qt];
    }
  }
  __syncthreads();

  if (wv == 0) {
    const size_t obase = ((size_t)(kz * NHEADS + h) * N_NODES + qb * 64);
    #pragma unroll
    for (int qt = 0; qt < 4; ++qt) {
      #pragma unroll
      for (int r = 0; r < 4; ++r) {
        const int q = qt * 16 + lg * 4 + r;
        float o = oacc[qt][r] + red_o[0][q][lc] + red_o[1][q][lc] + red_o[2][q][lc];
        Opart[(obase + q) * 16 + lc] = o;
      }
      if (lg == 0) {
        const int q = qt * 16 + lc;
        Wpart[obase + q] = wsum[qt] + red_w[0][q] + red_w[1][q] + red_w[2][q];
      }
    }
  }
}

// combine: attn_out[n][h*16+d] = sum_s Opart[s][h][n][d] / sum_s Wpart[s][h][n]
__global__ __launch_bounds__(256) void attn_combine(const float* __restrict__ Opart,
                                                    const float* __restrict__ Wpart,
                                                    float* __restrict__ attn_out) {
  int i = blockIdx.x * 256 + threadIdx.x;  // 0 .. 4*8192*4-1
  int dq = i & 3;
  int hn = i >> 2;
  int h = hn >> 13;
  int n = hn & 8191;
  float4 acc = make_float4(0.f, 0.f, 0.f, 0.f);
  float ws = 0.f;
  #pragma unroll
  for (int s = 0; s < KSPLIT; ++s) {
    const size_t row = ((size_t)(s * NHEADS + h) * N_NODES + n);
    float4 v = *reinterpret_cast<const float4*>(Opart + row * 16 + dq * 4);
    acc.x += v.x; acc.y += v.y; acc.z += v.z; acc.w += v.w;
    ws += Wpart[row];
  }
  float inv = 1.f / ws;
  float4 o = make_float4(acc.x * inv, acc.y * inv, acc.z * inv, acc.w * inv);
  *reinterpret_cast<float4*>(attn_out + (size_t)n * 64 + h * 16 + dq * 4) = o;
}

// ---------------- GCN aggregation ----------------
// C=256: 2 rows per block, 2 waves per row (even/odd edge split), LDS combine.

template <bool RELU>
__global__ __launch_bounds__(256) void aggregate2(const float* __restrict__ hw,
                                                  const int* __restrict__ csr,
                                                  const int* __restrict__ row_off,
                                                  const int* __restrict__ deg,
                                                  const float* __restrict__ dinv,
                                                  const float* __restrict__ bias,
                                                  float* __restrict__ out) {
  __shared__ __align__(16) float part[2][256];
  const int t = threadIdx.x;
  const int rw = t >> 7;          // row within block (0..1)
  const int wh = (t >> 6) & 1;    // wave half (even/odd edges)
  const int l = t & 63;
  const int r = blockIdx.x * 2 + rw;
  const float dr = dinv[r];
  const int off = row_off[r];
  const int cnt = deg[r] - 1;
  const int c = l << 2;

  float ax, ay, az, aw;
  if (wh == 0) {
    float4 a = *reinterpret_cast<const float4*>(hw + (size_t)r * 256 + c);
    ax = dr * a.x; ay = dr * a.y; az = dr * a.z; aw = dr * a.w;
  } else {
    ax = ay = az = aw = 0.f;
  }
  for (int e = wh; e < cnt; e += 2) {
    int s = csr[off + e];
    float wsc = dinv[s];
    float4 hv = *reinterpret_cast<const float4*>(hw + (size_t)s * 256 + c);
    ax += wsc * hv.x; ay += wsc * hv.y; az += wsc * hv.z; aw += wsc * hv.w;
  }
  if (wh == 1)
    *reinterpret_cast<float4*>(&part[rw][c]) = make_float4(ax, ay, az, aw);
  __syncthreads();
  if (wh == 0) {
    float4 p = *reinterpret_cast<const float4*>(&part[rw][c]);
    float4 bv = *reinterpret_cast<const float4*>(bias + c);
    float4 o;
    o.x = dr * (ax + p.x) + bv.x;
    o.y = dr * (ay + p.y) + bv.y;
    o.z = dr * (az + p.z) + bv.z;
    o.w = dr * (aw + p.w) + bv.w;
    if (RELU) {
      o.x = fmaxf(o.x, 0.f); o.y = fmaxf(o.y, 0.f);
      o.z = fmaxf(o.z, 0.f); o.w = fmaxf(o.w, 0.f);
    }
    *reinterpret_cast<float4*>(out + (size_t)r * 256 + c) = o;
  }
}

// C=64: one wave per row (layer 3, small)
template <bool RELU>
__global__ __launch_bounds__(256) void aggregate64(const float* __restrict__ hw,
                                                   const int* __restrict__ csr,
                                                   const int* __restrict__ row_off,
                                                   const int* __restrict__ deg,
                                                   const float* __restrict__ dinv,
                                                   const float* __restrict__ bias,
                                                   float* __restrict__ out) {
  const int w = threadIdx.x >> 6, l = threadIdx.x & 63;
  const int r = blockIdx.x * 4 + w;
  const float dr = dinv[r];
  const int off = row_off[r];
  const int cnt = deg[r] - 1;
  float a = dr * hw[(size_t)r * 64 + l];
  for (int e = 0; e < cnt; ++e) {
    int s = csr[off + e];
    a += dinv[s] * hw[(size_t)s * 64 + l];
  }
  float o = dr * a + bias[l];
  if (RELU) o = fmaxf(o, 0.f);
  out[(size_t)r * 64 + l] = o;
}

// ---------------- launch ----------------

extern "C" void kernel_launch(void* const* d_in, const int* in_sizes, int n_in,
                              void* d_out, int out_size, void* d_ws, size_t ws_size,
                              hipStream_t stream) {
  const float* x          = (const float*)d_in[0];
  const int*   ei         = (const int*)d_in[1];
  const float* pe_w       = (const float*)d_in[2];
  const float* pe_b       = (const float*)d_in[3];
  const float* in_proj_w  = (const float*)d_in[4];
  const float* in_proj_b  = (const float*)d_in[5];
  const float* out_proj_w = (const float*)d_in[6];
  const float* out_proj_b = (const float*)d_in[7];
  const float* w1         = (const float*)d_in[8];
  const float* b1         = (const float*)d_in[9];
  const float* w2         = (const float*)d_in[10];
  const float* b2         = (const float*)d_in[11];
  const float* w3         = (const float*)d_in[12];
  const float* b3         = (const float*)d_in[13];

  const int* esrc = ei;
  const int* edst = ei + N_EDGES;

  char* ws = (char*)d_ws;
  size_t o = 0;
  auto take = [&](size_t n) {
    char* p = ws + o;
    o += (n + 255) & ~(size_t)255;
    return p;
  };
  float* pf       = (float*)take((size_t)N_NODES * PATH_DIM * 4);
  float* qkv      = (float*)take((size_t)N_NODES * 3 * PATH_DIM * 4);
  float* attn_out = (float*)take((size_t)N_NODES * PATH_DIM * 4);
  float* pa       = (float*)take((size_t)N_NODES * PATH_DIM * 4);
  float* hw       = (float*)take((size_t)N_NODES * HID * 4);   // 8 MB
  float* h1       = (float*)take((size_t)N_NODES * HID * 4);   // 8 MB (right after hw)
  float* h2       = (float*)take((size_t)N_NODES * HID * 4);   // 8 MB
  float* Wt_in    = (float*)take((size_t)3 * PATH_DIM * PATH_DIM * 4);
  float* Wt_out   = (float*)take((size_t)PATH_DIM * PATH_DIM * 4);
  float* dinv     = (float*)take((size_t)N_NODES * 4);
  int*   deg      = (int*)take((size_t)N_NODES * 4);
  int*   cursor   = (int*)take((size_t)N_NODES * 4);
  int*   row_off  = (int*)take((size_t)N_NODES * 4);
  int*   csr      = (int*)take((size_t)N_EDGES * 4);

  // bf16 attention operands alias h2 (dead until layer-2 aggregate): 5 MB <= 8 MB.
  ushort* Qbf = (ushort*)h2;
  ushort* Kbf = Qbf + (size_t)NHEADS * N_NODES * 32;
  ushort* Vtb = Kbf + (size_t)NHEADS * N_NODES * 32;
  // attention partials: Opart spans hw..h1 (16 MB, contiguous, dead during attn);
  // Wpart aliases pa (1 MB of 2 MB).
  float* Opart = hw;   // [KSPLIT][NHEADS][N_NODES][16] f32 = 16 MB
  float* Wpart = pa;   // [KSPLIT][NHEADS][N_NODES]     f32 = 1 MB

  init_graph<<<N_NODES / 256, 256, 0, stream>>>(deg, cursor);
  count_deg<<<N_EDGES / 256, 256, 0, stream>>>(edst, deg);
  scan_rows<<<1, 256, 0, stream>>>(deg, row_off, dinv);
  fill_csr<<<N_EDGES / 256, 256, 0, stream>>>(esrc, edst, row_off, cursor, csr);

  transpose_w<<<(192 * 64 + 255) / 256, 256, 0, stream>>>(in_proj_w, Wt_in, 192, 64);
  transpose_w<<<(64 * 64 + 255) / 256, 256, 0, stream>>>(out_proj_w, Wt_out, 64, 64);

  gemm_tile<false, true><<<dim3(1, 128), 256, 0, stream>>>(x, IN_DIM, nullptr, 0, pe_w, pe_b, pf, PATH_DIM);
  gemm_tile<false, true><<<dim3(3, 128), 256, 0, stream>>>(pf, PATH_DIM, nullptr, 0, Wt_in, in_proj_b, qkv, 3 * PATH_DIM);

  convert_qkv<<<(N_NODES * NHEADS) / 256, 256, 0, stream>>>(qkv, Qbf, Kbf, Vtb);
  attn_mfma5<<<dim3(128, 4, KSPLIT), 256, 0, stream>>>(Qbf, Kbf, Vtb, Opart, Wpart);
  attn_combine<<<(NHEADS * N_NODES * 4) / 256, 256, 0, stream>>>(Opart, Wpart, attn_out);

  gemm_tile<false, true><<<dim3(1, 128), 256, 0, stream>>>(attn_out, PATH_DIM, nullptr, 0, Wt_out, out_proj_b, pa, PATH_DIM);

  gemm_tile<false, false><<<dim3(4, 128), 256, 0, stream>>>(x, IN_DIM, pa, PATH_DIM, w1, nullptr, hw, HID);
  aggregate2<true><<<N_NODES / 2, 256, 0, stream>>>(hw, csr, row_off, deg, dinv, b1, h1);
  gemm_tile<false, false><<<dim3(4, 128), 256, 0, stream>>>(h1, HID, nullptr, 0, w2, nullptr, hw, HID);
  aggregate2<true><<<N_NODES / 2, 256, 0, stream>>>(hw, csr, row_off, deg, dinv, b2, h2);
  gemm_tile<false, false><<<dim3(1, 128), 256, 0, stream>>>(h2, HID, nullptr, 0, w3, nullptr, hw, OUT_DIM);
  aggregate64<false><<<N_NODES / 4, 256, 0, stream>>>(hw, csr, row_off, deg, dinv, b3, (float*)d_out);
}